// Round 6
// baseline (1443.861 us; speedup 1.0000x reference)
//
#include <hip/hip_runtime.h>
#include <hip/hip_bf16.h>

#define D_MODEL 256
#define N_LAYER 16
#define VOCAB 24
#define D_INNER 512
#define D_STATE 16
#define D_CONV 4
#define DT_RANK 16
#define BATCH 2
#define SEQ 2048
#define NTOK (BATCH*SEQ)   /* 4096 */
#define EPS 1e-5f
#define NC 128             /* scan chunks per sequence */
#define CL (SEQ/NC)        /* 16 tokens per chunk */
#define NSC (BATCH*D_INNER*D_STATE)      /* 16384 scan chains */

typedef __hip_bfloat16 bf16;
typedef __attribute__((ext_vector_type(8))) short short8;
typedef __attribute__((ext_vector_type(4))) float f32x4;

__device__ __forceinline__ float silu(float v) { return v / (1.f + __expf(-v)); }
__device__ __forceinline__ float bf2f(bf16 v) { return __bfloat162float(v); }
__device__ __forceinline__ float bfs2f(short s) {         // raw bf16 bits -> f32
    return __uint_as_float(((unsigned)(unsigned short)s) << 16);
}
__device__ __forceinline__ short bfr(float x) {           // f32 -> bf16 RNE
    unsigned u = __float_as_uint(x);
    return (short)((u + 0x7fffu + ((u >> 16) & 1u)) >> 16);
}

// ------------- ALL-layer weight pre-convert: f32 -> bf16, one pass
__global__ void k_wcvt_all(const float* __restrict__ in_w, const float* __restrict__ out_w,
                           const float* __restrict__ x_w, short* __restrict__ in_wb,
                           short* __restrict__ out_wb, short* __restrict__ x_wb) {
    int idx = blockIdx.x * 256 + threadIdx.x;      // 6,684,672 total
    if (idx < 4194304) {
        in_wb[idx] = bfr(in_w[idx]);
    } else if (idx < 4194304 + 2097152) {
        int j = idx - 4194304;
        out_wb[j] = bfr(out_w[j]);
    } else {
        int j = idx - 4194304 - 2097152;           // < 393216
        x_wb[j] = bfr(x_w[j]);
    }
}

// -------------------------------- embedding; also seeds nsum (row sumsq) for layer 0
__global__ void k_embed(const int* __restrict__ ids, const float* __restrict__ emb,
                        float* __restrict__ residual, float* __restrict__ nsum) {
    __shared__ float wred[4];
    int tok = blockIdx.x, c = threadIdx.x;         // grid = NTOK, 256 thr
    float v = emb[ids[tok] * D_MODEL + c];
    residual[tok * 256 + c] = v;
    float s = v * v;
    #pragma unroll
    for (int off = 32; off >= 1; off >>= 1) s += __shfl_xor(s, off);
    if ((c & 63) == 0) wred[c >> 6] = s;
    __syncthreads();
    if (c == 0) {
        float tot = wred[0] + wred[1] + wred[2] + wred[3];
        *(float4*)(nsum + (size_t)tok * 4) = make_float4(tot, 0.f, 0.f, 0.f);
    }
}

// ------------------------------------------- final rmsnorm -> bf16 hn (standalone)
__global__ void k_rmsnorm(const float* __restrict__ residual, const float* __restrict__ w,
                          bf16* __restrict__ hn) {
    __shared__ float wred[4];
    int tok = blockIdx.x, c = threadIdx.x;
    float v = residual[tok * 256 + c];
    float s = v * v;
    #pragma unroll
    for (int off = 32; off >= 1; off >>= 1) s += __shfl_xor(s, off);
    if ((c & 63) == 0) wred[c >> 6] = s;
    __syncthreads();
    float tot = wred[0] + wred[1] + wred[2] + wred[3];
    float scale = rsqrtf(tot * (1.f / 256.f) + EPS);
    hn[tok * 256 + c] = __float2bfloat16(v * scale * w[c]);
}

// ---- gemm1 MFMA with FUSED rmsnorm, BK=64: A = rmsnorm(residual)*norm_w -> bf16
// [NTOK,256] @ [1024,256]^T -> xh/zb bf16
__global__ __launch_bounds__(256) void k_gemm1_mfma(const float* __restrict__ Rres,
                                                    const float* __restrict__ nsum,
                                                    const float* __restrict__ nw,
                                                    const short* __restrict__ W16,
                                                    bf16* __restrict__ xh,
                                                    bf16* __restrict__ zb) {
    __shared__ short AsL[64 * 72];   // [row][72] bf16, 64 K-cols pad->72
    __shared__ short WsL[64 * 72];
    const int bm = blockIdx.x * 64, bn = blockIdx.y * 64;
    const int tid = threadIdx.x;
    const int wave = tid >> 6, lane = tid & 63;
    const int wm = (wave & 1) * 32, wn = (wave >> 1) * 32;
    const int quad = lane >> 4, lr = lane & 15;
    const int srow = tid >> 2, skq = (tid & 3) * 16;  // 64 rows x 16 cols/thread
    const float4 ns = *(const float4*)(nsum + (size_t)(bm + srow) * 4);
    const float scale = rsqrtf((ns.x + ns.y + ns.z + ns.w) * (1.f / 256.f) + EPS);
    f32x4 acc[2][2] = {};
    for (int k0 = 0; k0 < 256; k0 += 64) {
        float av[16], wv[16];
        #pragma unroll
        for (int q = 0; q < 4; q++) {
            *(float4*)&av[q*4] = *(const float4*)(Rres + (size_t)(bm + srow) * 256 + k0 + skq + q * 4);
            *(float4*)&wv[q*4] = *(const float4*)(nw + k0 + skq + q * 4);
        }
        short8 a8[2];
        #pragma unroll
        for (int h = 0; h < 2; h++)
            #pragma unroll
            for (int j = 0; j < 8; j++) a8[h][j] = bfr(av[h*8+j] * scale * wv[h*8+j]);
        short8 w8[2];
        w8[0] = *(const short8*)(W16 + (size_t)(bn + srow) * 256 + k0 + skq);
        w8[1] = *(const short8*)(W16 + (size_t)(bn + srow) * 256 + k0 + skq + 8);
        __syncthreads();
        *(short8*)&AsL[srow * 72 + skq] = a8[0];
        *(short8*)&AsL[srow * 72 + skq + 8] = a8[1];
        *(short8*)&WsL[srow * 72 + skq] = w8[0];
        *(short8*)&WsL[srow * 72 + skq + 8] = w8[1];
        __syncthreads();
        #pragma unroll
        for (int kh = 0; kh < 2; kh++) {
            short8 af[2], bf[2];
            #pragma unroll
            for (int i = 0; i < 2; i++) {
                af[i] = *(const short8*)&AsL[(wm + i * 16 + lr) * 72 + kh * 32 + quad * 8];
                bf[i] = *(const short8*)&WsL[(wn + i * 16 + lr) * 72 + kh * 32 + quad * 8];
            }
            #pragma unroll
            for (int mi = 0; mi < 2; mi++)
                #pragma unroll
                for (int ni = 0; ni < 2; ni++)
                    acc[mi][ni] = __builtin_amdgcn_mfma_f32_16x16x32_bf16(
                        af[mi], bf[ni], acc[mi][ni], 0, 0, 0);
        }
    }
    #pragma unroll
    for (int mi = 0; mi < 2; mi++) {
        #pragma unroll
        for (int ni = 0; ni < 2; ni++) {
            int gcol = bn + wn + ni * 16 + lr;
            #pragma unroll
            for (int r = 0; r < 4; r++) {
                int grow = bm + wm + mi * 16 + quad * 4 + r;
                float v = acc[mi][ni][r];
                if (bn < 512) xh[(size_t)grow * 512 + gcol] = __float2bfloat16(v);
                else          zb[(size_t)grow * 512 + gcol - 512] = __float2bfloat16(v);
            }
        }
    }
}

// ---- gemm2 MFMA, BK=64: residual += [NTOK,512]bf16 @ [256,512]^T bf16
// FUSED epilogue: per-row partial sumsq of the UPDATED residual -> nsum[tok][bny]
__global__ __launch_bounds__(256) void k_gemm2_mfma(const bf16* __restrict__ Abf,
                                                    const short* __restrict__ W16,
                                                    float* __restrict__ residual,
                                                    float* __restrict__ nsum) {
    __shared__ short AsL[64 * 72];
    __shared__ short WsL[64 * 72];
    __shared__ float rsum[64][2];
    const short* A16 = (const short*)Abf;
    const int bm = blockIdx.x * 64, bn = blockIdx.y * 64;
    const int tid = threadIdx.x;
    const int wave = tid >> 6, lane = tid & 63;
    const int wm = (wave & 1) * 32, wn = (wave >> 1) * 32;
    const int quad = lane >> 4, lr = lane & 15;
    const int srow = tid >> 2, skq = (tid & 3) * 16;
    f32x4 acc[2][2] = {};
    for (int k0 = 0; k0 < 512; k0 += 64) {
        short8 a8[2], w8[2];
        a8[0] = *(const short8*)(A16 + (size_t)(bm + srow) * 512 + k0 + skq);
        a8[1] = *(const short8*)(A16 + (size_t)(bm + srow) * 512 + k0 + skq + 8);
        w8[0] = *(const short8*)(W16 + (size_t)(bn + srow) * 512 + k0 + skq);
        w8[1] = *(const short8*)(W16 + (size_t)(bn + srow) * 512 + k0 + skq + 8);
        __syncthreads();
        *(short8*)&AsL[srow * 72 + skq] = a8[0];
        *(short8*)&AsL[srow * 72 + skq + 8] = a8[1];
        *(short8*)&WsL[srow * 72 + skq] = w8[0];
        *(short8*)&WsL[srow * 72 + skq + 8] = w8[1];
        __syncthreads();
        #pragma unroll
        for (int kh = 0; kh < 2; kh++) {
            short8 af[2], bf[2];
            #pragma unroll
            for (int i = 0; i < 2; i++) {
                af[i] = *(const short8*)&AsL[(wm + i * 16 + lr) * 72 + kh * 32 + quad * 8];
                bf[i] = *(const short8*)&WsL[(wn + i * 16 + lr) * 72 + kh * 32 + quad * 8];
            }
            #pragma unroll
            for (int mi = 0; mi < 2; mi++)
                #pragma unroll
                for (int ni = 0; ni < 2; ni++)
                    acc[mi][ni] = __builtin_amdgcn_mfma_f32_16x16x32_bf16(
                        af[mi], bf[ni], acc[mi][ni], 0, 0, 0);
        }
    }
    float sq[2][4] = {};
    #pragma unroll
    for (int mi = 0; mi < 2; mi++) {
        #pragma unroll
        for (int ni = 0; ni < 2; ni++) {
            int gcol = bn + wn + ni * 16 + lr;
            #pragma unroll
            for (int r = 0; r < 4; r++) {
                int grow = bm + wm + mi * 16 + quad * 4 + r;
                size_t idx = (size_t)grow * 256 + gcol;
                float v = residual[idx] + acc[mi][ni][r];
                residual[idx] = v;
                sq[mi][r] += v * v;
            }
        }
    }
    #pragma unroll
    for (int off = 1; off < 16; off <<= 1) {
        #pragma unroll
        for (int mi = 0; mi < 2; mi++)
            #pragma unroll
            for (int r = 0; r < 4; r++)
                sq[mi][r] += __shfl_xor(sq[mi][r], off);
    }
    if (lr == 0) {
        #pragma unroll
        for (int mi = 0; mi < 2; mi++)
            #pragma unroll
            for (int r = 0; r < 4; r++)
                rsum[wm + mi * 16 + quad * 4 + r][wave >> 1] = sq[mi][r];
    }
    __syncthreads();
    if (tid < 64)
        nsum[(size_t)(bm + tid) * 4 + blockIdx.y] = rsum[tid][0] + rsum[tid][1];
}

// ---------------- depthwise conv + silu: thread = (d, 4 consecutive tokens)
__global__ void k_conv(const bf16* __restrict__ xh, const float* __restrict__ cw,
                       const float* __restrict__ cb, bf16* __restrict__ xb) {
    int gid = blockIdx.x * 256 + threadIdx.x;      // 512 * NTOK/4 = 524288
    int d = gid & 511;
    int tq = gid >> 9;                             // 0..1023
    int tok0 = tq * 4;                             // 4 | 2048: no batch crossing
    int b = tok0 >> 11, l0 = tok0 & 2047;
    float4 cwv = *(const float4*)(cw + d * 4);
    float cbv = cb[d];
    const bf16* base = xh + ((size_t)(b << 11)) * 512 + d;
    float xv[7];
    #pragma unroll
    for (int i = 0; i < 7; i++) {
        int lt = l0 - 3 + i;
        xv[i] = (lt >= 0) ? bf2f(base[(size_t)lt * 512]) : 0.f;
    }
    bf16* dst = xb + (size_t)tok0 * 512 + d;
    #pragma unroll
    for (int t = 0; t < 4; t++) {
        float acc = cbv + xv[t] * cwv.x + xv[t+1] * cwv.y + xv[t+2] * cwv.z + xv[t+3] * cwv.w;
        dst[(size_t)t * 512] = __float2bfloat16(silu(acc));
    }
}

// ---------------- x_proj MFMA, M-tile 32 (128 blocks): dbc[NTOK,48] = xb @ xw^T
__global__ __launch_bounds__(256) void k_xproj_mfma(const bf16* __restrict__ Abf,
                                                    const short* __restrict__ W16,
                                                    float* __restrict__ dbc) {
    __shared__ short AsL[32 * 40];
    __shared__ short WsL[64 * 40];
    const short* A16 = (const short*)Abf;
    const int bm = blockIdx.x * 32;
    const int tid = threadIdx.x;
    const int wave = tid >> 6, lane = tid & 63;
    const int wm = (wave & 1) * 16, wn = (wave >> 1) * 32;
    const int quad = lane >> 4, lr = lane & 15;
    const int srow = tid >> 2, skq = (tid & 3) * 8;   // srow 0..63
    f32x4 acc[2] = {};
    for (int k0 = 0; k0 < 512; k0 += 32) {
        short8 a8, w8;
        if (srow < 32) a8 = *(const short8*)(A16 + (size_t)(bm + srow) * 512 + k0 + skq);
        if (srow < 48) w8 = *(const short8*)(W16 + (size_t)srow * 512 + k0 + skq);
        __syncthreads();
        if (srow < 32) *(short8*)&AsL[srow * 40 + skq] = a8;
        if (srow < 48) *(short8*)&WsL[srow * 40 + skq] = w8;
        __syncthreads();
        short8 af = *(const short8*)&AsL[(wm + lr) * 40 + quad * 8];
        #pragma unroll
        for (int ni = 0; ni < 2; ni++) {
            short8 bfv = *(const short8*)&WsL[(wn + ni * 16 + lr) * 40 + quad * 8];
            acc[ni] = __builtin_amdgcn_mfma_f32_16x16x32_bf16(af, bfv, acc[ni], 0, 0, 0);
        }
    }
    #pragma unroll
    for (int ni = 0; ni < 2; ni++) {
        int gcol = wn + ni * 16 + lr;
        if (gcol < 48) {
            #pragma unroll
            for (int r = 0; r < 4; r++) {
                int grow = bm + wm + quad * 4 + r;
                dbc[(size_t)grow * 48 + gcol] = acc[ni][r];
            }
        }
    }
}

// -------- scan phase A: thread = (b,d,chunk); dt recomputed identically in scanC,
// so no dt export. 16 s-states in registers.
__global__ __launch_bounds__(64) void k_scanA(const bf16* __restrict__ xb,
                                              const float* __restrict__ dbc,
                                              const float* __restrict__ dtw,
                                              const float* __restrict__ dtb,
                                              const float* __restrict__ a_log,
                                              float* __restrict__ Aprod,
                                              float* __restrict__ Hfin) {
    int gid = blockIdx.x * 64 + threadIdx.x;       // 1024*NC = 131072
    int bd = gid & 1023;                           // d fast -> coalesced
    int c = gid >> 10;
    int d = bd & 511, b = bd >> 9;
    float A[16], h[16], ap[16], wdt[16];
    #pragma unroll
    for (int q = 0; q < 4; q++)
        *(float4*)&wdt[q*4] = *(const float4*)(dtw + d * 16 + q * 4);
    #pragma unroll
    for (int s = 0; s < 16; s++) {
        A[s] = -__expf(a_log[d * 16 + s]);
        h[s] = 0.f; ap[s] = 1.f;
    }
    float bdt = dtb[d];
    int tok0 = b * SEQ + c * CL;
    const bf16* xp = xb + (size_t)tok0 * 512 + d;
    const float* rp = dbc + (size_t)tok0 * 48;
    for (int t = 0; t < CL; t++) {
        float rv[32];
        #pragma unroll
        for (int q = 0; q < 8; q++) *(float4*)&rv[q*4] = *(const float4*)(rp + t * 48 + q * 4);
        float dtr = bdt;
        #pragma unroll
        for (int r = 0; r < 16; r++) dtr = fmaf(rv[r], wdt[r], dtr);
        float dtv = (dtr > 20.f) ? dtr : __logf(1.f + __expf(dtr));
        float u = dtv * bf2f(xp[t * 512]);
        #pragma unroll
        for (int s = 0; s < 16; s++) {
            float dA = __expf(dtv * A[s]);
            h[s] = fmaf(dA, h[s], u * rv[16 + s]);
            ap[s] *= dA;
        }
    }
    float* Ap = Aprod + (size_t)c * NSC + bd * 16;
    float* Hp = Hfin  + (size_t)c * NSC + bd * 16;
    #pragma unroll
    for (int q = 0; q < 4; q++) {
        *(float4*)(Ap + q * 4) = make_float4(ap[q*4], ap[q*4+1], ap[q*4+2], ap[q*4+3]);
        *(float4*)(Hp + q * 4) = make_float4(h[q*4], h[q*4+1], h[q*4+2], h[q*4+3]);
    }
}

// ---------------- scan phase B: serial combine over chunks, register-batched
__global__ __launch_bounds__(64) void k_scanB(const float* __restrict__ Aprod,
                                              float* __restrict__ Hfin) {
    int chain = blockIdx.x * 64 + threadIdx.x;     // NSC
    float h = 0.f;
    for (int cg = 0; cg < NC; cg += 16) {
        float a[16], f[16];
        #pragma unroll
        for (int j = 0; j < 16; j++) {
            size_t i = (size_t)(cg + j) * NSC + chain;
            a[j] = Aprod[i];
            f[j] = Hfin[i];
        }
        #pragma unroll
        for (int j = 0; j < 16; j++) {
            size_t i = (size_t)(cg + j) * NSC + chain;
            Hfin[i] = h;
            h = fmaf(a[j], h, f[j]);
        }
    }
}

// -------- scan phase C: rescan from start state; dt recomputed bit-identically
__global__ __launch_bounds__(64) void k_scanC(const bf16* __restrict__ xb,
                                              const bf16* __restrict__ zb,
                                              const float* __restrict__ dbc,
                                              const float* __restrict__ dtw,
                                              const float* __restrict__ dtb,
                                              const float* __restrict__ a_log,
                                              const float* __restrict__ Dp,
                                              const float* __restrict__ Hstart,
                                              bf16* __restrict__ yb) {
    int gid = blockIdx.x * 64 + threadIdx.x;       // 131072
    int bd = gid & 1023;
    int c = gid >> 10;
    int d = bd & 511, b = bd >> 9;
    float A[16], h[16], wdt[16];
    const float* Hp = Hstart + (size_t)c * NSC + bd * 16;
    #pragma unroll
    for (int q = 0; q < 4; q++)
        *(float4*)&wdt[q*4] = *(const float4*)(dtw + d * 16 + q * 4);
    #pragma unroll
    for (int s = 0; s < 16; s++) {
        A[s] = -__expf(a_log[d * 16 + s]);
        h[s] = Hp[s];
    }
    float bdt = dtb[d];
    float Dv = Dp[d];
    int tok0 = b * SEQ + c * CL;
    const bf16* xp = xb + (size_t)tok0 * 512 + d;
    const bf16* zp = zb + (size_t)tok0 * 512 + d;
    const float* rp = dbc + (size_t)tok0 * 48;     // dt at +0, B at +16, C at +32
    bf16* yp = yb + (size_t)tok0 * 512 + d;
    for (int t = 0; t < CL; t++) {
        float rv[48];
        #pragma unroll
        for (int q = 0; q < 12; q++) *(float4*)&rv[q*4] = *(const float4*)(rp + t * 48 + q * 4);
        float dtr = bdt;
        #pragma unroll
        for (int r = 0; r < 16; r++) dtr = fmaf(rv[r], wdt[r], dtr);
        float dtv = (dtr > 20.f) ? dtr : __logf(1.f + __expf(dtr));
        float xv = bf2f(xp[t * 512]);
        float u = dtv * xv;
        float sum = 0.f;
        #pragma unroll
        for (int s = 0; s < 16; s++) {
            float dA = __expf(dtv * A[s]);
            h[s] = fmaf(dA, h[s], u * rv[16 + s]);
            sum = fmaf(h[s], rv[32 + s], sum);
        }
        float zv = bf2f(zp[t * 512]);
        yp[t * 512] = __float2bfloat16((sum + Dv * xv) * silu(zv));
    }
}

// ---------------------------------------------------------------- lm head
__global__ void k_head(const bf16* __restrict__ hn, const float* __restrict__ lw,
                       float* __restrict__ out) {
    int idx = blockIdx.x * 256 + threadIdx.x;      // NTOK*20 = 81920
    int tok = idx / 20, v = idx % 20;
    const short* a = (const short*)(hn + (size_t)tok * 256);
    const float* w = lw + (size_t)v * 256;
    float acc = 0.f;
    for (int k = 0; k < 256; k += 8) {
        short8 a8 = *(const short8*)(a + k);
        #pragma unroll
        for (int j = 0; j < 8; j++) acc = fmaf(bfs2f(a8[j]), w[k + j], acc);
    }
    out[idx] = acc;
}

extern "C" void kernel_launch(void* const* d_in, const int* in_sizes, int n_in,
                              void* d_out, int out_size, void* d_ws, size_t ws_size,
                              hipStream_t stream) {
    const int*   ids    = (const int*)d_in[0];
    const float* emb    = (const float*)d_in[1];
    const float* in_w   = (const float*)d_in[2];
    const float* conv_w = (const float*)d_in[3];
    const float* conv_b = (const float*)d_in[4];
    const float* x_w    = (const float*)d_in[5];
    const float* dt_w   = (const float*)d_in[6];
    const float* dt_b   = (const float*)d_in[7];
    const float* a_log  = (const float*)d_in[8];
    const float* d_skip = (const float*)d_in[9];
    const float* out_w  = (const float*)d_in[10];
    const float* norm_w = (const float*)d_in[11];
    const float* norm_f = (const float*)d_in[12];
    const float* lm_w   = (const float*)d_in[13];
    float* out = (float*)d_out;

    // ---- workspace layout ----
    char* ws = (char*)d_ws;
    float* residual = (float*)(ws + 0);            // 4 MB
    bf16*  hn       = (bf16*) (ws + 4194304);      // 2 MB
    bf16*  xh       = (bf16*) (ws + 6291456);      // 4 MB (alias: yb)
    bf16*  zb       = (bf16*) (ws + 10485760);     // 4 MB
    bf16*  xb       = (bf16*) (ws + 14680064);     // 4 MB
    float* dbc      = (float*)(ws + 18874368);     // 768 KB
    float* Aprod    = (float*)(ws + 23855104);     // 8 MB
    float* Hfin     = (float*)(ws + 32243712);     // 8 MB
    short* in_wb    = (short*)(ws + 40632320);     // 8 MB  (16 layers bf16)
    short* out_wb   = (short*)(ws + 49020928);     // 4 MB
    short* x_wb     = (short*)(ws + 53215232);     // 768 KB
    float* nsum     = (float*)(ws + 54001664);     // 64 KB [tok][4] -> end 54,067,200
    bf16*  yb       = xh;

    k_wcvt_all<<<6684672 / 256, 256, 0, stream>>>(in_w, out_w, x_w, in_wb, out_wb, x_wb);
    k_embed<<<NTOK, 256, 0, stream>>>(ids, emb, residual, nsum);

    for (int i = 0; i < N_LAYER; i++) {
        dim3 g1(NTOK / 64, 1024 / 64);
        k_gemm1_mfma<<<g1, 256, 0, stream>>>(residual, nsum, norm_w + i * D_MODEL,
                                             in_wb + (size_t)i * 262144, xh, zb);
        k_conv<<<(512 * NTOK / 4) / 256, 256, 0, stream>>>(
            xh, conv_w + (size_t)i * 512 * 4, conv_b + (size_t)i * 512, xb);
        k_xproj_mfma<<<NTOK / 32, 256, 0, stream>>>(xb, x_wb + (size_t)i * 24576, dbc);
        k_scanA<<<(1024 * NC) / 64, 64, 0, stream>>>(
            xb, dbc, dt_w + (size_t)i * 512 * 16, dt_b + (size_t)i * 512,
            a_log + (size_t)i * 512 * 16, Aprod, Hfin);
        k_scanB<<<NSC / 64, 64, 0, stream>>>(Aprod, Hfin);
        k_scanC<<<(1024 * NC) / 64, 64, 0, stream>>>(
            xb, zb, dbc, dt_w + (size_t)i * 512 * 16, dt_b + (size_t)i * 512,
            a_log + (size_t)i * 512 * 16, d_skip + (size_t)i * 512, Hfin, yb);
        dim3 g2(NTOK / 64, 256 / 64);
        k_gemm2_mfma<<<g2, 256, 0, stream>>>(yb, out_wb + (size_t)i * 131072,
                                             residual, nsum);
    }

    k_rmsnorm<<<NTOK, 256, 0, stream>>>(residual, norm_f, hn);
    k_head<<<320, 256, 0, stream>>>(hn, lm_w, out);
}

// Round 7
// 1368.983 us; speedup vs baseline: 1.0547x; 1.0547x over previous
//
#include <hip/hip_runtime.h>
#include <hip/hip_bf16.h>

#define D_MODEL 256
#define N_LAYER 16
#define VOCAB 24
#define D_INNER 512
#define D_STATE 16
#define D_CONV 4
#define DT_RANK 16
#define BATCH 2
#define SEQ 2048
#define NTOK (BATCH*SEQ)   /* 4096 */
#define EPS 1e-5f
#define NC 128             /* scan chunks per sequence */
#define CL (SEQ/NC)        /* 16 tokens per chunk */
#define NSC (BATCH*D_INNER*D_STATE)      /* 16384 scan chains */

typedef __hip_bfloat16 bf16;
typedef __attribute__((ext_vector_type(8))) short short8;
typedef __attribute__((ext_vector_type(4))) float f32x4;

__device__ __forceinline__ float silu(float v) { return v / (1.f + __expf(-v)); }
__device__ __forceinline__ float bf2f(bf16 v) { return __bfloat162float(v); }
__device__ __forceinline__ float bfs2f(short s) {         // raw bf16 bits -> f32
    return __uint_as_float(((unsigned)(unsigned short)s) << 16);
}
__device__ __forceinline__ short bfr(float x) {           // f32 -> bf16 RNE
    unsigned u = __float_as_uint(x);
    return (short)((u + 0x7fffu + ((u >> 16) & 1u)) >> 16);
}

// ------------- ALL-layer weight pre-convert: f32 -> bf16, one pass
__global__ void k_wcvt_all(const float* __restrict__ in_w, const float* __restrict__ out_w,
                           const float* __restrict__ x_w, short* __restrict__ in_wb,
                           short* __restrict__ out_wb, short* __restrict__ x_wb) {
    int idx = blockIdx.x * 256 + threadIdx.x;      // 6,684,672 total
    if (idx < 4194304) {
        in_wb[idx] = bfr(in_w[idx]);
    } else if (idx < 4194304 + 2097152) {
        int j = idx - 4194304;
        out_wb[j] = bfr(out_w[j]);
    } else {
        int j = idx - 4194304 - 2097152;           // < 393216
        x_wb[j] = bfr(x_w[j]);
    }
}

// -------------------------------- embedding; also seeds nsum (row sumsq) for layer 0
__global__ void k_embed(const int* __restrict__ ids, const float* __restrict__ emb,
                        float* __restrict__ residual, float* __restrict__ nsum) {
    __shared__ float wred[4];
    int tok = blockIdx.x, c = threadIdx.x;         // grid = NTOK, 256 thr
    float v = emb[ids[tok] * D_MODEL + c];
    residual[tok * 256 + c] = v;
    float s = v * v;
    #pragma unroll
    for (int off = 32; off >= 1; off >>= 1) s += __shfl_xor(s, off);
    if ((c & 63) == 0) wred[c >> 6] = s;
    __syncthreads();
    if (c == 0) {
        float tot = wred[0] + wred[1] + wred[2] + wred[3];
        *(float4*)(nsum + (size_t)tok * 4) = make_float4(tot, 0.f, 0.f, 0.f);
    }
}

// ------------------------------------------- final rmsnorm -> bf16 hn (standalone)
__global__ void k_rmsnorm(const float* __restrict__ residual, const float* __restrict__ w,
                          bf16* __restrict__ hn) {
    __shared__ float wred[4];
    int tok = blockIdx.x, c = threadIdx.x;
    float v = residual[tok * 256 + c];
    float s = v * v;
    #pragma unroll
    for (int off = 32; off >= 1; off >>= 1) s += __shfl_xor(s, off);
    if ((c & 63) == 0) wred[c >> 6] = s;
    __syncthreads();
    float tot = wred[0] + wred[1] + wred[2] + wred[3];
    float scale = rsqrtf(tot * (1.f / 256.f) + EPS);
    hn[tok * 256 + c] = __float2bfloat16(v * scale * w[c]);
}

// ---- gemm1 MFMA with FUSED rmsnorm (BK=32, R3-verified): A = rmsnorm(residual)*nw
// [NTOK,256] @ [1024,256]^T -> xh/zb bf16
__global__ __launch_bounds__(256) void k_gemm1_mfma(const float* __restrict__ Rres,
                                                    const float* __restrict__ nsum,
                                                    const float* __restrict__ nw,
                                                    const short* __restrict__ W16,
                                                    bf16* __restrict__ xh,
                                                    bf16* __restrict__ zb) {
    __shared__ short AsL[64 * 40];   // [row][40] bf16, pad 32->40
    __shared__ short WsL[64 * 40];
    const int bm = blockIdx.x * 64, bn = blockIdx.y * 64;
    const int tid = threadIdx.x;
    const int wave = tid >> 6, lane = tid & 63;
    const int wm = (wave & 1) * 32, wn = (wave >> 1) * 32;
    const int quad = lane >> 4, lr = lane & 15;
    const int srow = tid >> 2, skq = (tid & 3) * 8;
    const float4 ns = *(const float4*)(nsum + (size_t)(bm + srow) * 4);
    const float scale = rsqrtf((ns.x + ns.y + ns.z + ns.w) * (1.f / 256.f) + EPS);
    f32x4 acc[2][2] = {};
    for (int k0 = 0; k0 < 256; k0 += 32) {
        float av[8], wv[8];
        *(float4*)&av[0] = *(const float4*)(Rres + (size_t)(bm + srow) * 256 + k0 + skq);
        *(float4*)&av[4] = *(const float4*)(Rres + (size_t)(bm + srow) * 256 + k0 + skq + 4);
        *(float4*)&wv[0] = *(const float4*)(nw + k0 + skq);
        *(float4*)&wv[4] = *(const float4*)(nw + k0 + skq + 4);
        short8 a8;
        #pragma unroll
        for (int j = 0; j < 8; j++) a8[j] = bfr(av[j] * scale * wv[j]);
        short8 w8 = *(const short8*)(W16 + (size_t)(bn + srow) * 256 + k0 + skq);
        __syncthreads();
        *(short8*)&AsL[srow * 40 + skq] = a8;
        *(short8*)&WsL[srow * 40 + skq] = w8;
        __syncthreads();
        short8 af[2], bf[2];
        #pragma unroll
        for (int i = 0; i < 2; i++) {
            af[i] = *(const short8*)&AsL[(wm + i * 16 + lr) * 40 + quad * 8];
            bf[i] = *(const short8*)&WsL[(wn + i * 16 + lr) * 40 + quad * 8];
        }
        #pragma unroll
        for (int mi = 0; mi < 2; mi++)
            #pragma unroll
            for (int ni = 0; ni < 2; ni++)
                acc[mi][ni] = __builtin_amdgcn_mfma_f32_16x16x32_bf16(
                    af[mi], bf[ni], acc[mi][ni], 0, 0, 0);
    }
    #pragma unroll
    for (int mi = 0; mi < 2; mi++) {
        #pragma unroll
        for (int ni = 0; ni < 2; ni++) {
            int gcol = bn + wn + ni * 16 + lr;
            #pragma unroll
            for (int r = 0; r < 4; r++) {
                int grow = bm + wm + mi * 16 + quad * 4 + r;
                float v = acc[mi][ni][r];
                if (bn < 512) xh[(size_t)grow * 512 + gcol] = __float2bfloat16(v);
                else          zb[(size_t)grow * 512 + gcol - 512] = __float2bfloat16(v);
            }
        }
    }
}

// ---- gemm2 MFMA (BK=32, R3-verified): residual += [NTOK,512]bf16 @ [256,512]^T
// FUSED epilogue: per-row partial sumsq of the UPDATED residual -> nsum[tok][bny]
__global__ __launch_bounds__(256) void k_gemm2_mfma(const bf16* __restrict__ Abf,
                                                    const short* __restrict__ W16,
                                                    float* __restrict__ residual,
                                                    float* __restrict__ nsum) {
    __shared__ short AsL[64 * 40];
    __shared__ short WsL[64 * 40];
    __shared__ float rsum[64][2];
    const short* A16 = (const short*)Abf;
    const int bm = blockIdx.x * 64, bn = blockIdx.y * 64;
    const int tid = threadIdx.x;
    const int wave = tid >> 6, lane = tid & 63;
    const int wm = (wave & 1) * 32, wn = (wave >> 1) * 32;
    const int quad = lane >> 4, lr = lane & 15;
    const int srow = tid >> 2, skq = (tid & 3) * 8;
    f32x4 acc[2][2] = {};
    for (int k0 = 0; k0 < 512; k0 += 32) {
        short8 a8 = *(const short8*)(A16 + (size_t)(bm + srow) * 512 + k0 + skq);
        short8 w8 = *(const short8*)(W16 + (size_t)(bn + srow) * 512 + k0 + skq);
        __syncthreads();
        *(short8*)&AsL[srow * 40 + skq] = a8;
        *(short8*)&WsL[srow * 40 + skq] = w8;
        __syncthreads();
        short8 af[2], bf[2];
        #pragma unroll
        for (int i = 0; i < 2; i++) {
            af[i] = *(const short8*)&AsL[(wm + i * 16 + lr) * 40 + quad * 8];
            bf[i] = *(const short8*)&WsL[(wn + i * 16 + lr) * 40 + quad * 8];
        }
        #pragma unroll
        for (int mi = 0; mi < 2; mi++)
            #pragma unroll
            for (int ni = 0; ni < 2; ni++)
                acc[mi][ni] = __builtin_amdgcn_mfma_f32_16x16x32_bf16(
                    af[mi], bf[ni], acc[mi][ni], 0, 0, 0);
    }
    float sq[2][4] = {};
    #pragma unroll
    for (int mi = 0; mi < 2; mi++) {
        #pragma unroll
        for (int ni = 0; ni < 2; ni++) {
            int gcol = bn + wn + ni * 16 + lr;
            #pragma unroll
            for (int r = 0; r < 4; r++) {
                int grow = bm + wm + mi * 16 + quad * 4 + r;
                size_t idx = (size_t)grow * 256 + gcol;
                float v = residual[idx] + acc[mi][ni][r];
                residual[idx] = v;
                sq[mi][r] += v * v;
            }
        }
    }
    #pragma unroll
    for (int off = 1; off < 16; off <<= 1) {
        #pragma unroll
        for (int mi = 0; mi < 2; mi++)
            #pragma unroll
            for (int r = 0; r < 4; r++)
                sq[mi][r] += __shfl_xor(sq[mi][r], off);
    }
    if (lr == 0) {
        #pragma unroll
        for (int mi = 0; mi < 2; mi++)
            #pragma unroll
            for (int r = 0; r < 4; r++)
                rsum[wm + mi * 16 + quad * 4 + r][wave >> 1] = sq[mi][r];
    }
    __syncthreads();
    if (tid < 64)
        nsum[(size_t)(bm + tid) * 4 + blockIdx.y] = rsum[tid][0] + rsum[tid][1];
}

// ---- FUSED conv+silu + x_proj MFMA. M-tile 16 (256 blocks = 1/CU).
// Prologue: conv computed once (vectorized short8), written to LDS tile + xb.
// W pre-loaded to registers (48 rows, L2-hot). K-loop: 16 x {ds_read + MFMA},
// no barriers. Conv arithmetic identical to the old k_conv (same expression).
__global__ __launch_bounds__(256) void k_convxproj(const bf16* __restrict__ xh,
                                                   const float* __restrict__ cw,
                                                   const float* __restrict__ cb,
                                                   const short* __restrict__ W16,
                                                   bf16* __restrict__ xb,
                                                   float* __restrict__ dbc) {
    __shared__ short Cs[16][520];            // conv output tile, pad 512->520
    const int bm = blockIdx.x * 16;          // token tile (never crosses batch)
    const int tid = threadIdx.x;
    const int wave = tid >> 6, lane = tid & 63;
    const int quad = lane >> 4, lr = lane & 15;
    const int wn = wave * 16;                // output col tile (wave 3 idle in MFMA)

    // ---- W rows wn..wn+15 into registers: lane (quad,lr) holds row wn+lr,
    //      cols quad*8 + 32k (k=0..15) -> exactly the per-step B-fragment.
    short8 wreg[16];
    if (wn < 48) {
        const short* wp = W16 + (size_t)(wn + lr) * 512 + quad * 8;
        #pragma unroll
        for (int k = 0; k < 16; k++) wreg[k] = *(const short8*)(wp + k * 32);
    }

    // ---- conv prologue: thread = (8 d-lanes, 4 token rows)
    {
        const int d8 = (tid & 63) * 8;
        const int rg = (tid >> 6) * 4;           // 0,4,8,12
        const int lbase = (bm & 2047) + rg;      // local seq pos of first out row
        const int gbase = bm + rg;               // global token of first out row
        float xv[7][8];
        #pragma unroll
        for (int i = 0; i < 7; i++) {
            int l = lbase - 3 + i;
            if (l >= 0) {
                short8 r8 = *(const short8*)((const short*)xh +
                               (size_t)(gbase - 3 + i) * 512 + d8);
                #pragma unroll
                for (int j = 0; j < 8; j++) xv[i][j] = bfs2f(r8[j]);
            } else {
                #pragma unroll
                for (int j = 0; j < 8; j++) xv[i][j] = 0.f;
            }
        }
        float cwv[8][4], cbv[8];
        #pragma unroll
        for (int j = 0; j < 8; j++) {
            *(float4*)&cwv[j][0] = *(const float4*)(cw + (d8 + j) * 4);
            cbv[j] = cb[d8 + j];
        }
        #pragma unroll
        for (int t = 0; t < 4; t++) {
            short8 o;
            #pragma unroll
            for (int j = 0; j < 8; j++) {
                float acc = cbv[j] + xv[t][j] * cwv[j][0] + xv[t+1][j] * cwv[j][1]
                                   + xv[t+2][j] * cwv[j][2] + xv[t+3][j] * cwv[j][3];
                o[j] = bfr(silu(acc));
            }
            *(short8*)&Cs[rg + t][d8] = o;
            *(short8*)((short*)xb + (size_t)(gbase + t) * 512 + d8) = o;
        }
    }
    __syncthreads();

    // ---- MFMA: 16 K-steps, zero barriers
    if (wn < 48) {
        f32x4 acc = {};
        #pragma unroll
        for (int k = 0; k < 16; k++) {
            short8 af = *(const short8*)&Cs[lr][k * 32 + quad * 8];
            acc = __builtin_amdgcn_mfma_f32_16x16x32_bf16(af, wreg[k], acc, 0, 0, 0);
        }
        int gcol = wn + lr;
        #pragma unroll
        for (int r = 0; r < 4; r++)
            dbc[(size_t)(bm + quad * 4 + r) * 48 + gcol] = acc[r];
    }
}

// -------- scan phase A: thread = (b,d,chunk); dt recomputed identically in scanC,
// so no dt export. 16 s-states in registers.
__global__ __launch_bounds__(64) void k_scanA(const bf16* __restrict__ xb,
                                              const float* __restrict__ dbc,
                                              const float* __restrict__ dtw,
                                              const float* __restrict__ dtb,
                                              const float* __restrict__ a_log,
                                              float* __restrict__ Aprod,
                                              float* __restrict__ Hfin) {
    int gid = blockIdx.x * 64 + threadIdx.x;       // 1024*NC = 131072
    int bd = gid & 1023;                           // d fast -> coalesced
    int c = gid >> 10;
    int d = bd & 511, b = bd >> 9;
    float A[16], h[16], ap[16], wdt[16];
    #pragma unroll
    for (int q = 0; q < 4; q++)
        *(float4*)&wdt[q*4] = *(const float4*)(dtw + d * 16 + q * 4);
    #pragma unroll
    for (int s = 0; s < 16; s++) {
        A[s] = -__expf(a_log[d * 16 + s]);
        h[s] = 0.f; ap[s] = 1.f;
    }
    float bdt = dtb[d];
    int tok0 = b * SEQ + c * CL;
    const bf16* xp = xb + (size_t)tok0 * 512 + d;
    const float* rp = dbc + (size_t)tok0 * 48;
    for (int t = 0; t < CL; t++) {
        float rv[32];
        #pragma unroll
        for (int q = 0; q < 8; q++) *(float4*)&rv[q*4] = *(const float4*)(rp + t * 48 + q * 4);
        float dtr = bdt;
        #pragma unroll
        for (int r = 0; r < 16; r++) dtr = fmaf(rv[r], wdt[r], dtr);
        float dtv = (dtr > 20.f) ? dtr : __logf(1.f + __expf(dtr));
        float u = dtv * bf2f(xp[t * 512]);
        #pragma unroll
        for (int s = 0; s < 16; s++) {
            float dA = __expf(dtv * A[s]);
            h[s] = fmaf(dA, h[s], u * rv[16 + s]);
            ap[s] *= dA;
        }
    }
    float* Ap = Aprod + (size_t)c * NSC + bd * 16;
    float* Hp = Hfin  + (size_t)c * NSC + bd * 16;
    #pragma unroll
    for (int q = 0; q < 4; q++) {
        *(float4*)(Ap + q * 4) = make_float4(ap[q*4], ap[q*4+1], ap[q*4+2], ap[q*4+3]);
        *(float4*)(Hp + q * 4) = make_float4(h[q*4], h[q*4+1], h[q*4+2], h[q*4+3]);
    }
}

// ---------------- scan phase B: serial combine over chunks, register-batched
__global__ __launch_bounds__(64) void k_scanB(const float* __restrict__ Aprod,
                                              float* __restrict__ Hfin) {
    int chain = blockIdx.x * 64 + threadIdx.x;     // NSC
    float h = 0.f;
    for (int cg = 0; cg < NC; cg += 16) {
        float a[16], f[16];
        #pragma unroll
        for (int j = 0; j < 16; j++) {
            size_t i = (size_t)(cg + j) * NSC + chain;
            a[j] = Aprod[i];
            f[j] = Hfin[i];
        }
        #pragma unroll
        for (int j = 0; j < 16; j++) {
            size_t i = (size_t)(cg + j) * NSC + chain;
            Hfin[i] = h;
            h = fmaf(a[j], h, f[j]);
        }
    }
}

// -------- scan phase C: rescan from start state; dt recomputed bit-identically
__global__ __launch_bounds__(64) void k_scanC(const bf16* __restrict__ xb,
                                              const bf16* __restrict__ zb,
                                              const float* __restrict__ dbc,
                                              const float* __restrict__ dtw,
                                              const float* __restrict__ dtb,
                                              const float* __restrict__ a_log,
                                              const float* __restrict__ Dp,
                                              const float* __restrict__ Hstart,
                                              bf16* __restrict__ yb) {
    int gid = blockIdx.x * 64 + threadIdx.x;       // 131072
    int bd = gid & 1023;
    int c = gid >> 10;
    int d = bd & 511, b = bd >> 9;
    float A[16], h[16], wdt[16];
    const float* Hp = Hstart + (size_t)c * NSC + bd * 16;
    #pragma unroll
    for (int q = 0; q < 4; q++)
        *(float4*)&wdt[q*4] = *(const float4*)(dtw + d * 16 + q * 4);
    #pragma unroll
    for (int s = 0; s < 16; s++) {
        A[s] = -__expf(a_log[d * 16 + s]);
        h[s] = Hp[s];
    }
    float bdt = dtb[d];
    float Dv = Dp[d];
    int tok0 = b * SEQ + c * CL;
    const bf16* xp = xb + (size_t)tok0 * 512 + d;
    const bf16* zp = zb + (size_t)tok0 * 512 + d;
    const float* rp = dbc + (size_t)tok0 * 48;     // dt at +0, B at +16, C at +32
    bf16* yp = yb + (size_t)tok0 * 512 + d;
    for (int t = 0; t < CL; t++) {
        float rv[48];
        #pragma unroll
        for (int q = 0; q < 12; q++) *(float4*)&rv[q*4] = *(const float4*)(rp + t * 48 + q * 4);
        float dtr = bdt;
        #pragma unroll
        for (int r = 0; r < 16; r++) dtr = fmaf(rv[r], wdt[r], dtr);
        float dtv = (dtr > 20.f) ? dtr : __logf(1.f + __expf(dtr));
        float xv = bf2f(xp[t * 512]);
        float u = dtv * xv;
        float sum = 0.f;
        #pragma unroll
        for (int s = 0; s < 16; s++) {
            float dA = __expf(dtv * A[s]);
            h[s] = fmaf(dA, h[s], u * rv[16 + s]);
            sum = fmaf(h[s], rv[32 + s], sum);
        }
        float zv = bf2f(zp[t * 512]);
        yp[t * 512] = __float2bfloat16((sum + Dv * xv) * silu(zv));
    }
}

// ---------------------------------------------------------------- lm head
__global__ void k_head(const bf16* __restrict__ hn, const float* __restrict__ lw,
                       float* __restrict__ out) {
    int idx = blockIdx.x * 256 + threadIdx.x;      // NTOK*20 = 81920
    int tok = idx / 20, v = idx % 20;
    const short* a = (const short*)(hn + (size_t)tok * 256);
    const float* w = lw + (size_t)v * 256;
    float acc = 0.f;
    for (int k = 0; k < 256; k += 8) {
        short8 a8 = *(const short8*)(a + k);
        #pragma unroll
        for (int j = 0; j < 8; j++) acc = fmaf(bfs2f(a8[j]), w[k + j], acc);
    }
    out[idx] = acc;
}

extern "C" void kernel_launch(void* const* d_in, const int* in_sizes, int n_in,
                              void* d_out, int out_size, void* d_ws, size_t ws_size,
                              hipStream_t stream) {
    const int*   ids    = (const int*)d_in[0];
    const float* emb    = (const float*)d_in[1];
    const float* in_w   = (const float*)d_in[2];
    const float* conv_w = (const float*)d_in[3];
    const float* conv_b = (const float*)d_in[4];
    const float* x_w    = (const float*)d_in[5];
    const float* dt_w   = (const float*)d_in[6];
    const float* dt_b   = (const float*)d_in[7];
    const float* a_log  = (const float*)d_in[8];
    const float* d_skip = (const float*)d_in[9];
    const float* out_w  = (const float*)d_in[10];
    const float* norm_w = (const float*)d_in[11];
    const float* norm_f = (const float*)d_in[12];
    const float* lm_w   = (const float*)d_in[13];
    float* out = (float*)d_out;

    // ---- workspace layout ----
    char* ws = (char*)d_ws;
    float* residual = (float*)(ws + 0);            // 4 MB
    bf16*  hn       = (bf16*) (ws + 4194304);      // 2 MB
    bf16*  xh       = (bf16*) (ws + 6291456);      // 4 MB (alias: yb)
    bf16*  zb       = (bf16*) (ws + 10485760);     // 4 MB
    bf16*  xb       = (bf16*) (ws + 14680064);     // 4 MB
    float* dbc      = (float*)(ws + 18874368);     // 768 KB
    float* Aprod    = (float*)(ws + 23855104);     // 8 MB
    float* Hfin     = (float*)(ws + 32243712);     // 8 MB
    short* in_wb    = (short*)(ws + 40632320);     // 8 MB  (16 layers bf16)
    short* out_wb   = (short*)(ws + 49020928);     // 4 MB
    short* x_wb     = (short*)(ws + 53215232);     // 768 KB
    float* nsum     = (float*)(ws + 54001664);     // 64 KB [tok][4] -> end 54,067,200
    bf16*  yb       = xh;

    k_wcvt_all<<<6684672 / 256, 256, 0, stream>>>(in_w, out_w, x_w, in_wb, out_wb, x_wb);
    k_embed<<<NTOK, 256, 0, stream>>>(ids, emb, residual, nsum);

    for (int i = 0; i < N_LAYER; i++) {
        dim3 g1(NTOK / 64, 1024 / 64);
        k_gemm1_mfma<<<g1, 256, 0, stream>>>(residual, nsum, norm_w + i * D_MODEL,
                                             in_wb + (size_t)i * 262144, xh, zb);
        k_convxproj<<<NTOK / 16, 256, 0, stream>>>(
            xh, conv_w + (size_t)i * 512 * 4, conv_b + (size_t)i * 512,
            x_wb + (size_t)i * 24576, xb, dbc);
        k_scanA<<<(1024 * NC) / 64, 64, 0, stream>>>(
            xb, dbc, dt_w + (size_t)i * 512 * 16, dt_b + (size_t)i * 512,
            a_log + (size_t)i * 512 * 16, Aprod, Hfin);
        k_scanB<<<NSC / 64, 64, 0, stream>>>(Aprod, Hfin);
        k_scanC<<<(1024 * NC) / 64, 64, 0, stream>>>(
            xb, zb, dbc, dt_w + (size_t)i * 512 * 16, dt_b + (size_t)i * 512,
            a_log + (size_t)i * 512 * 16, d_skip + (size_t)i * 512, Hfin, yb);
        dim3 g2(NTOK / 64, 256 / 64);
        k_gemm2_mfma<<<g2, 256, 0, stream>>>(yb, out_wb + (size_t)i * 131072,
                                             residual, nsum);
    }

    k_rmsnorm<<<NTOK, 256, 0, stream>>>(residual, norm_f, hn);
    k_head<<<320, 256, 0, stream>>>(hn, lm_w, out);
}

// Round 8
// 1339.488 us; speedup vs baseline: 1.0779x; 1.0220x over previous
//
#include <hip/hip_runtime.h>
#include <hip/hip_bf16.h>

#define D_MODEL 256
#define N_LAYER 16
#define VOCAB 24
#define D_INNER 512
#define D_STATE 16
#define D_CONV 4
#define DT_RANK 16
#define BATCH 2
#define SEQ 2048
#define NTOK (BATCH*SEQ)   /* 4096 */
#define EPS 1e-5f
#define NC 128             /* scan chunks per sequence */
#define CL (SEQ/NC)        /* 16 tokens per chunk */
#define NSC (BATCH*D_INNER*D_STATE)      /* 16384 scan chains */

typedef __hip_bfloat16 bf16;
typedef __attribute__((ext_vector_type(8))) short short8;
typedef __attribute__((ext_vector_type(4))) float f32x4;

__device__ __forceinline__ float silu(float v) { return v / (1.f + __expf(-v)); }
__device__ __forceinline__ float bf2f(bf16 v) { return __bfloat162float(v); }
__device__ __forceinline__ float bfs2f(short s) {         // raw bf16 bits -> f32
    return __uint_as_float(((unsigned)(unsigned short)s) << 16);
}
__device__ __forceinline__ short bfr(float x) {           // f32 -> bf16 RNE
    unsigned u = __float_as_uint(x);
    return (short)((u + 0x7fffu + ((u >> 16) & 1u)) >> 16);
}

// ------------- ALL-layer weight pre-convert: f32 -> bf16, one pass
__global__ void k_wcvt_all(const float* __restrict__ in_w, const float* __restrict__ out_w,
                           const float* __restrict__ x_w, short* __restrict__ in_wb,
                           short* __restrict__ out_wb, short* __restrict__ x_wb) {
    int idx = blockIdx.x * 256 + threadIdx.x;      // 6,684,672 total
    if (idx < 4194304) {
        in_wb[idx] = bfr(in_w[idx]);
    } else if (idx < 4194304 + 2097152) {
        int j = idx - 4194304;
        out_wb[j] = bfr(out_w[j]);
    } else {
        int j = idx - 4194304 - 2097152;           // < 393216
        x_wb[j] = bfr(x_w[j]);
    }
}

// -------------------------------- embedding; also seeds nsum (row sumsq) for layer 0
__global__ void k_embed(const int* __restrict__ ids, const float* __restrict__ emb,
                        float* __restrict__ residual, float* __restrict__ nsum) {
    __shared__ float wred[4];
    int tok = blockIdx.x, c = threadIdx.x;         // grid = NTOK, 256 thr
    float v = emb[ids[tok] * D_MODEL + c];
    residual[tok * 256 + c] = v;
    float s = v * v;
    #pragma unroll
    for (int off = 32; off >= 1; off >>= 1) s += __shfl_xor(s, off);
    if ((c & 63) == 0) wred[c >> 6] = s;
    __syncthreads();
    if (c == 0) {
        float tot = wred[0] + wred[1] + wred[2] + wred[3];
        *(float4*)(nsum + (size_t)tok * 4) = make_float4(tot, 0.f, 0.f, 0.f);
    }
}

// ------------------------------------------- final rmsnorm -> bf16 hn (standalone)
__global__ void k_rmsnorm(const float* __restrict__ residual, const float* __restrict__ w,
                          bf16* __restrict__ hn) {
    __shared__ float wred[4];
    int tok = blockIdx.x, c = threadIdx.x;
    float v = residual[tok * 256 + c];
    float s = v * v;
    #pragma unroll
    for (int off = 32; off >= 1; off >>= 1) s += __shfl_xor(s, off);
    if ((c & 63) == 0) wred[c >> 6] = s;
    __syncthreads();
    float tot = wred[0] + wred[1] + wred[2] + wred[3];
    float scale = rsqrtf(tot * (1.f / 256.f) + EPS);
    hn[tok * 256 + c] = __float2bfloat16(v * scale * w[c]);
}

// ---- gemm1 MFMA with FUSED rmsnorm, N-tile 128 (grid.y=8): halves A re-reads
// and normalize redundancy vs N-tile 64. A = rmsnorm(residual)*nw -> bf16.
// [NTOK,256] @ [1024,256]^T -> xh/zb bf16. Bit-identical arithmetic to R7.
__global__ __launch_bounds__(256) void k_gemm1_mfma(const float* __restrict__ Rres,
                                                    const float* __restrict__ nsum,
                                                    const float* __restrict__ nw,
                                                    const short* __restrict__ W16,
                                                    bf16* __restrict__ xh,
                                                    bf16* __restrict__ zb) {
    __shared__ short AsL[64 * 40];    // A tile [64 rows][32k pad->40]
    __shared__ short WsL[128 * 40];   // W tile [128 rows][32k pad->40]
    const int bm = blockIdx.x * 64, bn = blockIdx.y * 128;
    const int tid = threadIdx.x;
    const int wave = tid >> 6, lane = tid & 63;
    const int wm = (wave & 1) * 32, wn = (wave >> 1) * 32;
    const int quad = lane >> 4, lr = lane & 15;
    const int srow = tid >> 2, skq = (tid & 3) * 8;
    const float4 ns = *(const float4*)(nsum + (size_t)(bm + srow) * 4);
    const float scale = rsqrtf((ns.x + ns.y + ns.z + ns.w) * (1.f / 256.f) + EPS);
    f32x4 acc[2][2][2] = {};          // [nb][mi][ni]
    for (int k0 = 0; k0 < 256; k0 += 32) {
        float av[8], wv[8];
        *(float4*)&av[0] = *(const float4*)(Rres + (size_t)(bm + srow) * 256 + k0 + skq);
        *(float4*)&av[4] = *(const float4*)(Rres + (size_t)(bm + srow) * 256 + k0 + skq + 4);
        *(float4*)&wv[0] = *(const float4*)(nw + k0 + skq);
        *(float4*)&wv[4] = *(const float4*)(nw + k0 + skq + 4);
        short8 a8;
        #pragma unroll
        for (int j = 0; j < 8; j++) a8[j] = bfr(av[j] * scale * wv[j]);
        short8 w8[2];
        w8[0] = *(const short8*)(W16 + (size_t)(bn + srow) * 256 + k0 + skq);
        w8[1] = *(const short8*)(W16 + (size_t)(bn + 64 + srow) * 256 + k0 + skq);
        __syncthreads();
        *(short8*)&AsL[srow * 40 + skq] = a8;
        *(short8*)&WsL[srow * 40 + skq] = w8[0];
        *(short8*)&WsL[(64 + srow) * 40 + skq] = w8[1];
        __syncthreads();
        short8 af[2], bf[2][2];
        #pragma unroll
        for (int i = 0; i < 2; i++)
            af[i] = *(const short8*)&AsL[(wm + i * 16 + lr) * 40 + quad * 8];
        #pragma unroll
        for (int nb = 0; nb < 2; nb++)
            #pragma unroll
            for (int i = 0; i < 2; i++)
                bf[nb][i] = *(const short8*)&WsL[(nb * 64 + wn + i * 16 + lr) * 40 + quad * 8];
        #pragma unroll
        for (int nb = 0; nb < 2; nb++)
            #pragma unroll
            for (int mi = 0; mi < 2; mi++)
                #pragma unroll
                for (int ni = 0; ni < 2; ni++)
                    acc[nb][mi][ni] = __builtin_amdgcn_mfma_f32_16x16x32_bf16(
                        af[mi], bf[nb][ni], acc[nb][mi][ni], 0, 0, 0);
    }
    #pragma unroll
    for (int nb = 0; nb < 2; nb++) {
        #pragma unroll
        for (int mi = 0; mi < 2; mi++) {
            #pragma unroll
            for (int ni = 0; ni < 2; ni++) {
                int gcol = bn + nb * 64 + wn + ni * 16 + lr;
                #pragma unroll
                for (int r = 0; r < 4; r++) {
                    int grow = bm + wm + mi * 16 + quad * 4 + r;
                    float v = acc[nb][mi][ni][r];
                    if (gcol < 512) xh[(size_t)grow * 512 + gcol] = __float2bfloat16(v);
                    else            zb[(size_t)grow * 512 + gcol - 512] = __float2bfloat16(v);
                }
            }
        }
    }
}

// ---- gemm2 MFMA (BK=32, R3-verified): residual += [NTOK,512]bf16 @ [256,512]^T
// FUSED epilogue: per-row partial sumsq of the UPDATED residual -> nsum[tok][bny]
__global__ __launch_bounds__(256) void k_gemm2_mfma(const bf16* __restrict__ Abf,
                                                    const short* __restrict__ W16,
                                                    float* __restrict__ residual,
                                                    float* __restrict__ nsum) {
    __shared__ short AsL[64 * 40];
    __shared__ short WsL[64 * 40];
    __shared__ float rsum[64][2];
    const short* A16 = (const short*)Abf;
    const int bm = blockIdx.x * 64, bn = blockIdx.y * 64;
    const int tid = threadIdx.x;
    const int wave = tid >> 6, lane = tid & 63;
    const int wm = (wave & 1) * 32, wn = (wave >> 1) * 32;
    const int quad = lane >> 4, lr = lane & 15;
    const int srow = tid >> 2, skq = (tid & 3) * 8;
    f32x4 acc[2][2] = {};
    for (int k0 = 0; k0 < 512; k0 += 32) {
        short8 a8 = *(const short8*)(A16 + (size_t)(bm + srow) * 512 + k0 + skq);
        short8 w8 = *(const short8*)(W16 + (size_t)(bn + srow) * 512 + k0 + skq);
        __syncthreads();
        *(short8*)&AsL[srow * 40 + skq] = a8;
        *(short8*)&WsL[srow * 40 + skq] = w8;
        __syncthreads();
        short8 af[2], bf[2];
        #pragma unroll
        for (int i = 0; i < 2; i++) {
            af[i] = *(const short8*)&AsL[(wm + i * 16 + lr) * 40 + quad * 8];
            bf[i] = *(const short8*)&WsL[(wn + i * 16 + lr) * 40 + quad * 8];
        }
        #pragma unroll
        for (int mi = 0; mi < 2; mi++)
            #pragma unroll
            for (int ni = 0; ni < 2; ni++)
                acc[mi][ni] = __builtin_amdgcn_mfma_f32_16x16x32_bf16(
                    af[mi], bf[ni], acc[mi][ni], 0, 0, 0);
    }
    float sq[2][4] = {};
    #pragma unroll
    for (int mi = 0; mi < 2; mi++) {
        #pragma unroll
        for (int ni = 0; ni < 2; ni++) {
            int gcol = bn + wn + ni * 16 + lr;
            #pragma unroll
            for (int r = 0; r < 4; r++) {
                int grow = bm + wm + mi * 16 + quad * 4 + r;
                size_t idx = (size_t)grow * 256 + gcol;
                float v = residual[idx] + acc[mi][ni][r];
                residual[idx] = v;
                sq[mi][r] += v * v;
            }
        }
    }
    #pragma unroll
    for (int off = 1; off < 16; off <<= 1) {
        #pragma unroll
        for (int mi = 0; mi < 2; mi++)
            #pragma unroll
            for (int r = 0; r < 4; r++)
                sq[mi][r] += __shfl_xor(sq[mi][r], off);
    }
    if (lr == 0) {
        #pragma unroll
        for (int mi = 0; mi < 2; mi++)
            #pragma unroll
            for (int r = 0; r < 4; r++)
                rsum[wm + mi * 16 + quad * 4 + r][wave >> 1] = sq[mi][r];
    }
    __syncthreads();
    if (tid < 64)
        nsum[(size_t)(bm + tid) * 4 + blockIdx.y] = rsum[tid][0] + rsum[tid][1];
}

// ---- FUSED conv+silu + x_proj MFMA. M-tile 16 (256 blocks = 1/CU).
// Prologue: conv computed once (vectorized short8), written to LDS tile + xb.
// W pre-loaded to registers (48 rows, L2-hot). K-loop: 16 x {ds_read + MFMA},
// no barriers. Conv arithmetic identical to the old k_conv (same expression).
__global__ __launch_bounds__(256) void k_convxproj(const bf16* __restrict__ xh,
                                                   const float* __restrict__ cw,
                                                   const float* __restrict__ cb,
                                                   const short* __restrict__ W16,
                                                   bf16* __restrict__ xb,
                                                   float* __restrict__ dbc) {
    __shared__ short Cs[16][520];            // conv output tile, pad 512->520
    const int bm = blockIdx.x * 16;          // token tile (never crosses batch)
    const int tid = threadIdx.x;
    const int wave = tid >> 6, lane = tid & 63;
    const int quad = lane >> 4, lr = lane & 15;
    const int wn = wave * 16;                // output col tile (wave 3 idle in MFMA)

    // ---- W rows wn..wn+15 into registers: lane (quad,lr) holds row wn+lr,
    //      cols quad*8 + 32k (k=0..15) -> exactly the per-step B-fragment.
    short8 wreg[16];
    if (wn < 48) {
        const short* wp = W16 + (size_t)(wn + lr) * 512 + quad * 8;
        #pragma unroll
        for (int k = 0; k < 16; k++) wreg[k] = *(const short8*)(wp + k * 32);
    }

    // ---- conv prologue: thread = (8 d-lanes, 4 token rows)
    {
        const int d8 = (tid & 63) * 8;
        const int rg = (tid >> 6) * 4;           // 0,4,8,12
        const int lbase = (bm & 2047) + rg;      // local seq pos of first out row
        const int gbase = bm + rg;               // global token of first out row
        float xv[7][8];
        #pragma unroll
        for (int i = 0; i < 7; i++) {
            int l = lbase - 3 + i;
            if (l >= 0) {
                short8 r8 = *(const short8*)((const short*)xh +
                               (size_t)(gbase - 3 + i) * 512 + d8);
                #pragma unroll
                for (int j = 0; j < 8; j++) xv[i][j] = bfs2f(r8[j]);
            } else {
                #pragma unroll
                for (int j = 0; j < 8; j++) xv[i][j] = 0.f;
            }
        }
        float cwv[8][4], cbv[8];
        #pragma unroll
        for (int j = 0; j < 8; j++) {
            *(float4*)&cwv[j][0] = *(const float4*)(cw + (d8 + j) * 4);
            cbv[j] = cb[d8 + j];
        }
        #pragma unroll
        for (int t = 0; t < 4; t++) {
            short8 o;
            #pragma unroll
            for (int j = 0; j < 8; j++) {
                float acc = cbv[j] + xv[t][j] * cwv[j][0] + xv[t+1][j] * cwv[j][1]
                                   + xv[t+2][j] * cwv[j][2] + xv[t+3][j] * cwv[j][3];
                o[j] = bfr(silu(acc));
            }
            *(short8*)&Cs[rg + t][d8] = o;
            *(short8*)((short*)xb + (size_t)(gbase + t) * 512 + d8) = o;
        }
    }
    __syncthreads();

    // ---- MFMA: 16 K-steps, zero barriers
    if (wn < 48) {
        f32x4 acc = {};
        #pragma unroll
        for (int k = 0; k < 16; k++) {
            short8 af = *(const short8*)&Cs[lr][k * 32 + quad * 8];
            acc = __builtin_amdgcn_mfma_f32_16x16x32_bf16(af, wreg[k], acc, 0, 0, 0);
        }
        int gcol = wn + lr;
        #pragma unroll
        for (int r = 0; r < 4; r++)
            dbc[(size_t)(bm + quad * 4 + r) * 48 + gcol] = acc[r];
    }
}

// -------- scan phase A: thread = (b,d,chunk); dt recomputed identically in scanC,
// so no dt export. 16 s-states in registers.
__global__ __launch_bounds__(64) void k_scanA(const bf16* __restrict__ xb,
                                              const float* __restrict__ dbc,
                                              const float* __restrict__ dtw,
                                              const float* __restrict__ dtb,
                                              const float* __restrict__ a_log,
                                              float* __restrict__ Aprod,
                                              float* __restrict__ Hfin) {
    int gid = blockIdx.x * 64 + threadIdx.x;       // 1024*NC = 131072
    int bd = gid & 1023;                           // d fast -> coalesced
    int c = gid >> 10;
    int d = bd & 511, b = bd >> 9;
    float A[16], h[16], ap[16], wdt[16];
    #pragma unroll
    for (int q = 0; q < 4; q++)
        *(float4*)&wdt[q*4] = *(const float4*)(dtw + d * 16 + q * 4);
    #pragma unroll
    for (int s = 0; s < 16; s++) {
        A[s] = -__expf(a_log[d * 16 + s]);
        h[s] = 0.f; ap[s] = 1.f;
    }
    float bdt = dtb[d];
    int tok0 = b * SEQ + c * CL;
    const bf16* xp = xb + (size_t)tok0 * 512 + d;
    const float* rp = dbc + (size_t)tok0 * 48;
    for (int t = 0; t < CL; t++) {
        float rv[32];
        #pragma unroll
        for (int q = 0; q < 8; q++) *(float4*)&rv[q*4] = *(const float4*)(rp + t * 48 + q * 4);
        float dtr = bdt;
        #pragma unroll
        for (int r = 0; r < 16; r++) dtr = fmaf(rv[r], wdt[r], dtr);
        float dtv = (dtr > 20.f) ? dtr : __logf(1.f + __expf(dtr));
        float u = dtv * bf2f(xp[t * 512]);
        #pragma unroll
        for (int s = 0; s < 16; s++) {
            float dA = __expf(dtv * A[s]);
            h[s] = fmaf(dA, h[s], u * rv[16 + s]);
            ap[s] *= dA;
        }
    }
    float* Ap = Aprod + (size_t)c * NSC + bd * 16;
    float* Hp = Hfin  + (size_t)c * NSC + bd * 16;
    #pragma unroll
    for (int q = 0; q < 4; q++) {
        *(float4*)(Ap + q * 4) = make_float4(ap[q*4], ap[q*4+1], ap[q*4+2], ap[q*4+3]);
        *(float4*)(Hp + q * 4) = make_float4(h[q*4], h[q*4+1], h[q*4+2], h[q*4+3]);
    }
}

// ---------------- scan phase B: serial combine over chunks, register-batched
__global__ __launch_bounds__(64) void k_scanB(const float* __restrict__ Aprod,
                                              float* __restrict__ Hfin) {
    int chain = blockIdx.x * 64 + threadIdx.x;     // NSC
    float h = 0.f;
    for (int cg = 0; cg < NC; cg += 16) {
        float a[16], f[16];
        #pragma unroll
        for (int j = 0; j < 16; j++) {
            size_t i = (size_t)(cg + j) * NSC + chain;
            a[j] = Aprod[i];
            f[j] = Hfin[i];
        }
        #pragma unroll
        for (int j = 0; j < 16; j++) {
            size_t i = (size_t)(cg + j) * NSC + chain;
            Hfin[i] = h;
            h = fmaf(a[j], h, f[j]);
        }
    }
}

// -------- scan phase C: rescan from start state; dt recomputed bit-identically
__global__ __launch_bounds__(64) void k_scanC(const bf16* __restrict__ xb,
                                              const bf16* __restrict__ zb,
                                              const float* __restrict__ dbc,
                                              const float* __restrict__ dtw,
                                              const float* __restrict__ dtb,
                                              const float* __restrict__ a_log,
                                              const float* __restrict__ Dp,
                                              const float* __restrict__ Hstart,
                                              bf16* __restrict__ yb) {
    int gid = blockIdx.x * 64 + threadIdx.x;       // 131072
    int bd = gid & 1023;
    int c = gid >> 10;
    int d = bd & 511, b = bd >> 9;
    float A[16], h[16], wdt[16];
    const float* Hp = Hstart + (size_t)c * NSC + bd * 16;
    #pragma unroll
    for (int q = 0; q < 4; q++)
        *(float4*)&wdt[q*4] = *(const float4*)(dtw + d * 16 + q * 4);
    #pragma unroll
    for (int s = 0; s < 16; s++) {
        A[s] = -__expf(a_log[d * 16 + s]);
        h[s] = Hp[s];
    }
    float bdt = dtb[d];
    float Dv = Dp[d];
    int tok0 = b * SEQ + c * CL;
    const bf16* xp = xb + (size_t)tok0 * 512 + d;
    const bf16* zp = zb + (size_t)tok0 * 512 + d;
    const float* rp = dbc + (size_t)tok0 * 48;     // dt at +0, B at +16, C at +32
    bf16* yp = yb + (size_t)tok0 * 512 + d;
    for (int t = 0; t < CL; t++) {
        float rv[48];
        #pragma unroll
        for (int q = 0; q < 12; q++) *(float4*)&rv[q*4] = *(const float4*)(rp + t * 48 + q * 4);
        float dtr = bdt;
        #pragma unroll
        for (int r = 0; r < 16; r++) dtr = fmaf(rv[r], wdt[r], dtr);
        float dtv = (dtr > 20.f) ? dtr : __logf(1.f + __expf(dtr));
        float xv = bf2f(xp[t * 512]);
        float u = dtv * xv;
        float sum = 0.f;
        #pragma unroll
        for (int s = 0; s < 16; s++) {
            float dA = __expf(dtv * A[s]);
            h[s] = fmaf(dA, h[s], u * rv[16 + s]);
            sum = fmaf(h[s], rv[32 + s], sum);
        }
        float zv = bf2f(zp[t * 512]);
        yp[t * 512] = __float2bfloat16((sum + Dv * xv) * silu(zv));
    }
}

// ---------------------------------------------------------------- lm head
__global__ void k_head(const bf16* __restrict__ hn, const float* __restrict__ lw,
                       float* __restrict__ out) {
    int idx = blockIdx.x * 256 + threadIdx.x;      // NTOK*20 = 81920
    int tok = idx / 20, v = idx % 20;
    const short* a = (const short*)(hn + (size_t)tok * 256);
    const float* w = lw + (size_t)v * 256;
    float acc = 0.f;
    for (int k = 0; k < 256; k += 8) {
        short8 a8 = *(const short8*)(a + k);
        #pragma unroll
        for (int j = 0; j < 8; j++) acc = fmaf(bfs2f(a8[j]), w[k + j], acc);
    }
    out[idx] = acc;
}

extern "C" void kernel_launch(void* const* d_in, const int* in_sizes, int n_in,
                              void* d_out, int out_size, void* d_ws, size_t ws_size,
                              hipStream_t stream) {
    const int*   ids    = (const int*)d_in[0];
    const float* emb    = (const float*)d_in[1];
    const float* in_w   = (const float*)d_in[2];
    const float* conv_w = (const float*)d_in[3];
    const float* conv_b = (const float*)d_in[4];
    const float* x_w    = (const float*)d_in[5];
    const float* dt_w   = (const float*)d_in[6];
    const float* dt_b   = (const float*)d_in[7];
    const float* a_log  = (const float*)d_in[8];
    const float* d_skip = (const float*)d_in[9];
    const float* out_w  = (const float*)d_in[10];
    const float* norm_w = (const float*)d_in[11];
    const float* norm_f = (const float*)d_in[12];
    const float* lm_w   = (const float*)d_in[13];
    float* out = (float*)d_out;

    // ---- workspace layout ----
    char* ws = (char*)d_ws;
    float* residual = (float*)(ws + 0);            // 4 MB
    bf16*  hn       = (bf16*) (ws + 4194304);      // 2 MB
    bf16*  xh       = (bf16*) (ws + 6291456);      // 4 MB (alias: yb)
    bf16*  zb       = (bf16*) (ws + 10485760);     // 4 MB
    bf16*  xb       = (bf16*) (ws + 14680064);     // 4 MB
    float* dbc      = (float*)(ws + 18874368);     // 768 KB
    float* Aprod    = (float*)(ws + 23855104);     // 8 MB
    float* Hfin     = (float*)(ws + 32243712);     // 8 MB
    short* in_wb    = (short*)(ws + 40632320);     // 8 MB  (16 layers bf16)
    short* out_wb   = (short*)(ws + 49020928);     // 4 MB
    short* x_wb     = (short*)(ws + 53215232);     // 768 KB
    float* nsum     = (float*)(ws + 54001664);     // 64 KB [tok][4] -> end 54,067,200
    bf16*  yb       = xh;

    k_wcvt_all<<<6684672 / 256, 256, 0, stream>>>(in_w, out_w, x_w, in_wb, out_wb, x_wb);
    k_embed<<<NTOK, 256, 0, stream>>>(ids, emb, residual, nsum);

    for (int i = 0; i < N_LAYER; i++) {
        dim3 g1(NTOK / 64, 1024 / 128);
        k_gemm1_mfma<<<g1, 256, 0, stream>>>(residual, nsum, norm_w + i * D_MODEL,
                                             in_wb + (size_t)i * 262144, xh, zb);
        k_convxproj<<<NTOK / 16, 256, 0, stream>>>(
            xh, conv_w + (size_t)i * 512 * 4, conv_b + (size_t)i * 512,
            x_wb + (size_t)i * 24576, xb, dbc);
        k_scanA<<<(1024 * NC) / 64, 64, 0, stream>>>(
            xb, dbc, dt_w + (size_t)i * 512 * 16, dt_b + (size_t)i * 512,
            a_log + (size_t)i * 512 * 16, Aprod, Hfin);
        k_scanB<<<NSC / 64, 64, 0, stream>>>(Aprod, Hfin);
        k_scanC<<<(1024 * NC) / 64, 64, 0, stream>>>(
            xb, zb, dbc, dt_w + (size_t)i * 512 * 16, dt_b + (size_t)i * 512,
            a_log + (size_t)i * 512 * 16, d_skip + (size_t)i * 512, Hfin, yb);
        dim3 g2(NTOK / 64, 256 / 64);
        k_gemm2_mfma<<<g2, 256, 0, stream>>>(yb, out_wb + (size_t)i * 131072,
                                             residual, nsum);
    }

    k_rmsnorm<<<NTOK, 256, 0, stream>>>(residual, norm_f, hn);
    k_head<<<320, 256, 0, stream>>>(hn, lm_w, out);
}

// Round 9
// 1216.462 us; speedup vs baseline: 1.1869x; 1.1011x over previous
//
#include <hip/hip_runtime.h>
#include <hip/hip_bf16.h>

#define D_MODEL 256
#define N_LAYER 16
#define VOCAB 24
#define D_INNER 512
#define D_STATE 16
#define D_CONV 4
#define DT_RANK 16
#define BATCH 2
#define SEQ 2048
#define NTOK (BATCH*SEQ)   /* 4096 */
#define EPS 1e-5f
#define NC 128             /* scan chunks per sequence */
#define CL (SEQ/NC)        /* 16 tokens per chunk */
#define NSC (BATCH*D_INNER*D_STATE)      /* 16384 scan chains */
#define WCVT_BLOCKS 26112  /* 6,684,672 / 256 */

typedef __hip_bfloat16 bf16;
typedef __attribute__((ext_vector_type(8))) short short8;
typedef __attribute__((ext_vector_type(4))) float f32x4;

__device__ __forceinline__ float silu(float v) { return v / (1.f + __expf(-v)); }
__device__ __forceinline__ float bf2f(bf16 v) { return __bfloat162float(v); }
__device__ __forceinline__ float bfs2f(short s) {         // raw bf16 bits -> f32
    return __uint_as_float(((unsigned)(unsigned short)s) << 16);
}
__device__ __forceinline__ short bfr(float x) {           // f32 -> bf16 RNE
    unsigned u = __float_as_uint(x);
    return (short)((u + 0x7fffu + ((u >> 16) & 1u)) >> 16);
}

// ---- init: weight bf16 pre-convert (blocks 0..26111) + embedding w/ nsum seed
__global__ void k_init(const float* __restrict__ in_w, const float* __restrict__ out_w,
                       const float* __restrict__ x_w, short* __restrict__ in_wb,
                       short* __restrict__ out_wb, short* __restrict__ x_wb,
                       const int* __restrict__ ids, const float* __restrict__ emb,
                       float* __restrict__ residual, float* __restrict__ nsum) {
    __shared__ float wred[4];
    if (blockIdx.x < WCVT_BLOCKS) {
        int idx = blockIdx.x * 256 + threadIdx.x;      // 6,684,672 total
        if (idx < 4194304) {
            in_wb[idx] = bfr(in_w[idx]);
        } else if (idx < 4194304 + 2097152) {
            int j = idx - 4194304;
            out_wb[j] = bfr(out_w[j]);
        } else {
            int j = idx - 4194304 - 2097152;           // < 393216
            x_wb[j] = bfr(x_w[j]);
        }
    } else {
        int tok = blockIdx.x - WCVT_BLOCKS, c = threadIdx.x;
        float v = emb[ids[tok] * D_MODEL + c];
        residual[tok * 256 + c] = v;
        float s = v * v;
        #pragma unroll
        for (int off = 32; off >= 1; off >>= 1) s += __shfl_xor(s, off);
        if ((c & 63) == 0) wred[c >> 6] = s;
        __syncthreads();
        if (c == 0) {
            float tot = wred[0] + wred[1] + wred[2] + wred[3];
            *(float4*)(nsum + (size_t)tok * 4) = make_float4(tot, 0.f, 0.f, 0.f);
        }
    }
}

// ---- gemm1 MFMA with FUSED rmsnorm, N-tile 128 (grid.y=8) [R8-verified]
__global__ __launch_bounds__(256) void k_gemm1_mfma(const float* __restrict__ Rres,
                                                    const float* __restrict__ nsum,
                                                    const float* __restrict__ nw,
                                                    const short* __restrict__ W16,
                                                    bf16* __restrict__ xh,
                                                    bf16* __restrict__ zb) {
    __shared__ short AsL[64 * 40];    // A tile [64 rows][32k pad->40]
    __shared__ short WsL[128 * 40];   // W tile [128 rows][32k pad->40]
    const int bm = blockIdx.x * 64, bn = blockIdx.y * 128;
    const int tid = threadIdx.x;
    const int wave = tid >> 6, lane = tid & 63;
    const int wm = (wave & 1) * 32, wn = (wave >> 1) * 32;
    const int quad = lane >> 4, lr = lane & 15;
    const int srow = tid >> 2, skq = (tid & 3) * 8;
    const float4 ns = *(const float4*)(nsum + (size_t)(bm + srow) * 4);
    const float scale = rsqrtf((ns.x + ns.y + ns.z + ns.w) * (1.f / 256.f) + EPS);
    f32x4 acc[2][2][2] = {};          // [nb][mi][ni]
    for (int k0 = 0; k0 < 256; k0 += 32) {
        float av[8], wv[8];
        *(float4*)&av[0] = *(const float4*)(Rres + (size_t)(bm + srow) * 256 + k0 + skq);
        *(float4*)&av[4] = *(const float4*)(Rres + (size_t)(bm + srow) * 256 + k0 + skq + 4);
        *(float4*)&wv[0] = *(const float4*)(nw + k0 + skq);
        *(float4*)&wv[4] = *(const float4*)(nw + k0 + skq + 4);
        short8 a8;
        #pragma unroll
        for (int j = 0; j < 8; j++) a8[j] = bfr(av[j] * scale * wv[j]);
        short8 w8[2];
        w8[0] = *(const short8*)(W16 + (size_t)(bn + srow) * 256 + k0 + skq);
        w8[1] = *(const short8*)(W16 + (size_t)(bn + 64 + srow) * 256 + k0 + skq);
        __syncthreads();
        *(short8*)&AsL[srow * 40 + skq] = a8;
        *(short8*)&WsL[srow * 40 + skq] = w8[0];
        *(short8*)&WsL[(64 + srow) * 40 + skq] = w8[1];
        __syncthreads();
        short8 af[2], bf[2][2];
        #pragma unroll
        for (int i = 0; i < 2; i++)
            af[i] = *(const short8*)&AsL[(wm + i * 16 + lr) * 40 + quad * 8];
        #pragma unroll
        for (int nb = 0; nb < 2; nb++)
            #pragma unroll
            for (int i = 0; i < 2; i++)
                bf[nb][i] = *(const short8*)&WsL[(nb * 64 + wn + i * 16 + lr) * 40 + quad * 8];
        #pragma unroll
        for (int nb = 0; nb < 2; nb++)
            #pragma unroll
            for (int mi = 0; mi < 2; mi++)
                #pragma unroll
                for (int ni = 0; ni < 2; ni++)
                    acc[nb][mi][ni] = __builtin_amdgcn_mfma_f32_16x16x32_bf16(
                        af[mi], bf[nb][ni], acc[nb][mi][ni], 0, 0, 0);
    }
    #pragma unroll
    for (int nb = 0; nb < 2; nb++) {
        #pragma unroll
        for (int mi = 0; mi < 2; mi++) {
            #pragma unroll
            for (int ni = 0; ni < 2; ni++) {
                int gcol = bn + nb * 64 + wn + ni * 16 + lr;
                #pragma unroll
                for (int r = 0; r < 4; r++) {
                    int grow = bm + wm + mi * 16 + quad * 4 + r;
                    float v = acc[nb][mi][ni][r];
                    if (gcol < 512) xh[(size_t)grow * 512 + gcol] = __float2bfloat16(v);
                    else            zb[(size_t)grow * 512 + gcol - 512] = __float2bfloat16(v);
                }
            }
        }
    }
}

// ---- gemm2 MFMA (BK=32) + fused nsum epilogue [R3-verified]
__global__ __launch_bounds__(256) void k_gemm2_mfma(const bf16* __restrict__ Abf,
                                                    const short* __restrict__ W16,
                                                    float* __restrict__ residual,
                                                    float* __restrict__ nsum) {
    __shared__ short AsL[64 * 40];
    __shared__ short WsL[64 * 40];
    __shared__ float rsum[64][2];
    const short* A16 = (const short*)Abf;
    const int bm = blockIdx.x * 64, bn = blockIdx.y * 64;
    const int tid = threadIdx.x;
    const int wave = tid >> 6, lane = tid & 63;
    const int wm = (wave & 1) * 32, wn = (wave >> 1) * 32;
    const int quad = lane >> 4, lr = lane & 15;
    const int srow = tid >> 2, skq = (tid & 3) * 8;
    f32x4 acc[2][2] = {};
    for (int k0 = 0; k0 < 512; k0 += 32) {
        short8 a8 = *(const short8*)(A16 + (size_t)(bm + srow) * 512 + k0 + skq);
        short8 w8 = *(const short8*)(W16 + (size_t)(bn + srow) * 512 + k0 + skq);
        __syncthreads();
        *(short8*)&AsL[srow * 40 + skq] = a8;
        *(short8*)&WsL[srow * 40 + skq] = w8;
        __syncthreads();
        short8 af[2], bf[2];
        #pragma unroll
        for (int i = 0; i < 2; i++) {
            af[i] = *(const short8*)&AsL[(wm + i * 16 + lr) * 40 + quad * 8];
            bf[i] = *(const short8*)&WsL[(wn + i * 16 + lr) * 40 + quad * 8];
        }
        #pragma unroll
        for (int mi = 0; mi < 2; mi++)
            #pragma unroll
            for (int ni = 0; ni < 2; ni++)
                acc[mi][ni] = __builtin_amdgcn_mfma_f32_16x16x32_bf16(
                    af[mi], bf[ni], acc[mi][ni], 0, 0, 0);
    }
    float sq[2][4] = {};
    #pragma unroll
    for (int mi = 0; mi < 2; mi++) {
        #pragma unroll
        for (int ni = 0; ni < 2; ni++) {
            int gcol = bn + wn + ni * 16 + lr;
            #pragma unroll
            for (int r = 0; r < 4; r++) {
                int grow = bm + wm + mi * 16 + quad * 4 + r;
                size_t idx = (size_t)grow * 256 + gcol;
                float v = residual[idx] + acc[mi][ni][r];
                residual[idx] = v;
                sq[mi][r] += v * v;
            }
        }
    }
    #pragma unroll
    for (int off = 1; off < 16; off <<= 1) {
        #pragma unroll
        for (int mi = 0; mi < 2; mi++)
            #pragma unroll
            for (int r = 0; r < 4; r++)
                sq[mi][r] += __shfl_xor(sq[mi][r], off);
    }
    if (lr == 0) {
        #pragma unroll
        for (int mi = 0; mi < 2; mi++)
            #pragma unroll
            for (int r = 0; r < 4; r++)
                rsum[wm + mi * 16 + quad * 4 + r][wave >> 1] = sq[mi][r];
    }
    __syncthreads();
    if (tid < 64)
        nsum[(size_t)(bm + tid) * 4 + blockIdx.y] = rsum[tid][0] + rsum[tid][1];
}

// ---- FUSED conv+silu + x_proj MFMA + scanA. M-tile 16 = exactly one scan chunk.
// Conv once (R7-verified pattern) -> Cs + xb; xproj MFMA -> dbc + LDS Ds;
// then 256 threads run scan phase A for the block's 512 d-chains (2/thread),
// reading dt/B coefficients as wave-uniform LDS broadcasts. All arithmetic
// bit-identical to the separate-kernel path (same fmaf/softplus/exp order).
__global__ __launch_bounds__(256) void k_cxs(const bf16* __restrict__ xh,
                                             const float* __restrict__ cw,
                                             const float* __restrict__ cb,
                                             const short* __restrict__ W16,
                                             const float* __restrict__ dtw,
                                             const float* __restrict__ dtb,
                                             const float* __restrict__ a_log,
                                             bf16* __restrict__ xb,
                                             float* __restrict__ dbc,
                                             float* __restrict__ Aprod,
                                             float* __restrict__ Hfin) {
    __shared__ short Cs[16][520];            // conv output tile, pad 512->520
    __shared__ float Ds[16][52];             // dbc tile, 48 cols pad->52
    const int bm = blockIdx.x * 16;          // token tile == scan chunk
    const int tid = threadIdx.x;
    const int wave = tid >> 6, lane = tid & 63;
    const int quad = lane >> 4, lr = lane & 15;
    const int wn = wave * 16;

    short8 wreg[16];
    if (wn < 48) {
        const short* wp = W16 + (size_t)(wn + lr) * 512 + quad * 8;
        #pragma unroll
        for (int k = 0; k < 16; k++) wreg[k] = *(const short8*)(wp + k * 32);
    }

    // ---- conv prologue: thread = (8 d-lanes, 4 token rows)
    {
        const int d8 = (tid & 63) * 8;
        const int rg = (tid >> 6) * 4;           // 0,4,8,12
        const int lbase = (bm & 2047) + rg;
        const int gbase = bm + rg;
        float xv[7][8];
        #pragma unroll
        for (int i = 0; i < 7; i++) {
            int l = lbase - 3 + i;
            if (l >= 0) {
                short8 r8 = *(const short8*)((const short*)xh +
                               (size_t)(gbase - 3 + i) * 512 + d8);
                #pragma unroll
                for (int j = 0; j < 8; j++) xv[i][j] = bfs2f(r8[j]);
            } else {
                #pragma unroll
                for (int j = 0; j < 8; j++) xv[i][j] = 0.f;
            }
        }
        float cwv[8][4], cbv[8];
        #pragma unroll
        for (int j = 0; j < 8; j++) {
            *(float4*)&cwv[j][0] = *(const float4*)(cw + (d8 + j) * 4);
            cbv[j] = cb[d8 + j];
        }
        #pragma unroll
        for (int t = 0; t < 4; t++) {
            short8 o;
            #pragma unroll
            for (int j = 0; j < 8; j++) {
                float acc = cbv[j] + xv[t][j] * cwv[j][0] + xv[t+1][j] * cwv[j][1]
                                   + xv[t+2][j] * cwv[j][2] + xv[t+3][j] * cwv[j][3];
                o[j] = bfr(silu(acc));
            }
            *(short8*)&Cs[rg + t][d8] = o;
            *(short8*)((short*)xb + (size_t)(gbase + t) * 512 + d8) = o;
        }
    }
    __syncthreads();

    // ---- xproj MFMA (waves 0..2), results -> dbc global + Ds LDS
    if (wn < 48) {
        f32x4 acc = {};
        #pragma unroll
        for (int k = 0; k < 16; k++) {
            short8 af = *(const short8*)&Cs[lr][k * 32 + quad * 8];
            acc = __builtin_amdgcn_mfma_f32_16x16x32_bf16(af, wreg[k], acc, 0, 0, 0);
        }
        int gcol = wn + lr;
        #pragma unroll
        for (int r = 0; r < 4; r++) {
            float v = acc[r];
            dbc[(size_t)(bm + quad * 4 + r) * 48 + gcol] = v;
            Ds[quad * 4 + r][gcol] = v;
        }
    }
    __syncthreads();

    // ---- scan phase A: 512 chains, 2 per thread (d = tid, tid+256), chunk c
    {
        const int b = bm >> 11;
        const int c = (bm & 2047) >> 4;
        float A[2][16], h[2][16], ap[2][16], wdt[2][16], bdt[2];
        #pragma unroll
        for (int ch = 0; ch < 2; ch++) {
            int d = tid + ch * 256;
            #pragma unroll
            for (int q = 0; q < 4; q++)
                *(float4*)&wdt[ch][q*4] = *(const float4*)(dtw + d * 16 + q * 4);
            #pragma unroll
            for (int s = 0; s < 16; s++) {
                A[ch][s] = -__expf(a_log[d * 16 + s]);
                h[ch][s] = 0.f; ap[ch][s] = 1.f;
            }
            bdt[ch] = dtb[d];
        }
        for (int t = 0; t < CL; t++) {
            float dtc[16], Bc[16];
            #pragma unroll
            for (int r = 0; r < 16; r++) dtc[r] = Ds[t][r];       // broadcast
            #pragma unroll
            for (int s = 0; s < 16; s++) Bc[s] = Ds[t][16 + s];   // broadcast
            #pragma unroll
            for (int ch = 0; ch < 2; ch++) {
                int d = tid + ch * 256;
                float dtr = bdt[ch];
                #pragma unroll
                for (int r = 0; r < 16; r++) dtr = fmaf(dtc[r], wdt[ch][r], dtr);
                float dtv = (dtr > 20.f) ? dtr : __logf(1.f + __expf(dtr));
                float u = dtv * bfs2f(((const short*)&Cs[t][0])[d]);
                #pragma unroll
                for (int s = 0; s < 16; s++) {
                    float dA = __expf(dtv * A[ch][s]);
                    h[ch][s] = fmaf(dA, h[ch][s], u * Bc[s]);
                    ap[ch][s] *= dA;
                }
            }
        }
        #pragma unroll
        for (int ch = 0; ch < 2; ch++) {
            int d = tid + ch * 256;
            int bd = b * 512 + d;
            float* Ap = Aprod + (size_t)c * NSC + (size_t)bd * 16;
            float* Hp = Hfin  + (size_t)c * NSC + (size_t)bd * 16;
            #pragma unroll
            for (int q = 0; q < 4; q++) {
                *(float4*)(Ap + q * 4) = make_float4(ap[ch][q*4], ap[ch][q*4+1],
                                                     ap[ch][q*4+2], ap[ch][q*4+3]);
                *(float4*)(Hp + q * 4) = make_float4(h[ch][q*4], h[ch][q*4+1],
                                                     h[ch][q*4+2], h[ch][q*4+3]);
            }
        }
    }
}

// ---------------- scan phase B: serial combine over chunks, register-batched
__global__ __launch_bounds__(64) void k_scanB(const float* __restrict__ Aprod,
                                              float* __restrict__ Hfin) {
    int chain = blockIdx.x * 64 + threadIdx.x;     // NSC
    float h = 0.f;
    for (int cg = 0; cg < NC; cg += 16) {
        float a[16], f[16];
        #pragma unroll
        for (int j = 0; j < 16; j++) {
            size_t i = (size_t)(cg + j) * NSC + chain;
            a[j] = Aprod[i];
            f[j] = Hfin[i];
        }
        #pragma unroll
        for (int j = 0; j < 16; j++) {
            size_t i = (size_t)(cg + j) * NSC + chain;
            Hfin[i] = h;
            h = fmaf(a[j], h, f[j]);
        }
    }
}

// -------- scan phase C: rescan from start state; dt recomputed bit-identically
__global__ __launch_bounds__(64) void k_scanC(const bf16* __restrict__ xb,
                                              const bf16* __restrict__ zb,
                                              const float* __restrict__ dbc,
                                              const float* __restrict__ dtw,
                                              const float* __restrict__ dtb,
                                              const float* __restrict__ a_log,
                                              const float* __restrict__ Dp,
                                              const float* __restrict__ Hstart,
                                              bf16* __restrict__ yb) {
    int gid = blockIdx.x * 64 + threadIdx.x;       // 131072
    int bd = gid & 1023;
    int c = gid >> 10;
    int d = bd & 511, b = bd >> 9;
    float A[16], h[16], wdt[16];
    const float* Hp = Hstart + (size_t)c * NSC + bd * 16;
    #pragma unroll
    for (int q = 0; q < 4; q++)
        *(float4*)&wdt[q*4] = *(const float4*)(dtw + d * 16 + q * 4);
    #pragma unroll
    for (int s = 0; s < 16; s++) {
        A[s] = -__expf(a_log[d * 16 + s]);
        h[s] = Hp[s];
    }
    float bdt = dtb[d];
    float Dv = Dp[d];
    int tok0 = b * SEQ + c * CL;
    const bf16* xp = xb + (size_t)tok0 * 512 + d;
    const bf16* zp = zb + (size_t)tok0 * 512 + d;
    const float* rp = dbc + (size_t)tok0 * 48;     // dt at +0, B at +16, C at +32
    bf16* yp = yb + (size_t)tok0 * 512 + d;
    for (int t = 0; t < CL; t++) {
        float rv[48];
        #pragma unroll
        for (int q = 0; q < 12; q++) *(float4*)&rv[q*4] = *(const float4*)(rp + t * 48 + q * 4);
        float dtr = bdt;
        #pragma unroll
        for (int r = 0; r < 16; r++) dtr = fmaf(rv[r], wdt[r], dtr);
        float dtv = (dtr > 20.f) ? dtr : __logf(1.f + __expf(dtr));
        float xv = bf2f(xp[t * 512]);
        float u = dtv * xv;
        float sum = 0.f;
        #pragma unroll
        for (int s = 0; s < 16; s++) {
            float dA = __expf(dtv * A[s]);
            h[s] = fmaf(dA, h[s], u * rv[16 + s]);
            sum = fmaf(h[s], rv[32 + s], sum);
        }
        float zv = bf2f(zp[t * 512]);
        yp[t * 512] = __float2bfloat16((sum + Dv * xv) * silu(zv));
    }
}

// ---- final rmsnorm + lm head fused: hn never leaves the block
__global__ void k_rmshead(const float* __restrict__ residual, const float* __restrict__ w,
                          const float* __restrict__ lw, float* __restrict__ out) {
    __shared__ float wred[4];
    __shared__ float hrow[256];
    int tok = blockIdx.x, c = threadIdx.x;
    float v = residual[tok * 256 + c];
    float s = v * v;
    #pragma unroll
    for (int off = 32; off >= 1; off >>= 1) s += __shfl_xor(s, off);
    if ((c & 63) == 0) wred[c >> 6] = s;
    __syncthreads();
    float tot = wred[0] + wred[1] + wred[2] + wred[3];
    float scale = rsqrtf(tot * (1.f / 256.f) + EPS);
    hrow[c] = bfs2f(bfr(v * scale * w[c]));    // bf16-rounded, same as old hn path
    __syncthreads();
    int wave = c >> 6, lane = c & 63;
    float4 hl = *(const float4*)&hrow[lane * 4];
    #pragma unroll
    for (int j = 0; j < 5; j++) {
        int vv = wave * 5 + j;
        float4 wl = *(const float4*)(lw + (size_t)vv * 256 + lane * 4);
        float p = hl.x * wl.x + hl.y * wl.y + hl.z * wl.z + hl.w * wl.w;
        #pragma unroll
        for (int off = 32; off >= 1; off >>= 1) p += __shfl_xor(p, off);
        if (lane == 0) out[(size_t)tok * 20 + vv] = p;
    }
}

extern "C" void kernel_launch(void* const* d_in, const int* in_sizes, int n_in,
                              void* d_out, int out_size, void* d_ws, size_t ws_size,
                              hipStream_t stream) {
    const int*   ids    = (const int*)d_in[0];
    const float* emb    = (const float*)d_in[1];
    const float* in_w   = (const float*)d_in[2];
    const float* conv_w = (const float*)d_in[3];
    const float* conv_b = (const float*)d_in[4];
    const float* x_w    = (const float*)d_in[5];
    const float* dt_w   = (const float*)d_in[6];
    const float* dt_b   = (const float*)d_in[7];
    const float* a_log  = (const float*)d_in[8];
    const float* d_skip = (const float*)d_in[9];
    const float* out_w  = (const float*)d_in[10];
    const float* norm_w = (const float*)d_in[11];
    const float* norm_f = (const float*)d_in[12];
    const float* lm_w   = (const float*)d_in[13];
    float* out = (float*)d_out;

    // ---- workspace layout ----
    char* ws = (char*)d_ws;
    float* residual = (float*)(ws + 0);            // 4 MB
    bf16*  xh       = (bf16*) (ws + 6291456);      // 4 MB (alias: yb)
    bf16*  zb       = (bf16*) (ws + 10485760);     // 4 MB
    bf16*  xb       = (bf16*) (ws + 14680064);     // 4 MB
    float* dbc      = (float*)(ws + 18874368);     // 768 KB
    float* Aprod    = (float*)(ws + 23855104);     // 8 MB
    float* Hfin     = (float*)(ws + 32243712);     // 8 MB
    short* in_wb    = (short*)(ws + 40632320);     // 8 MB  (16 layers bf16)
    short* out_wb   = (short*)(ws + 49020928);     // 4 MB
    short* x_wb     = (short*)(ws + 53215232);     // 768 KB
    float* nsum     = (float*)(ws + 54001664);     // 64 KB [tok][4]
    bf16*  yb       = xh;

    k_init<<<WCVT_BLOCKS + NTOK, 256, 0, stream>>>(in_w, out_w, x_w, in_wb, out_wb,
                                                   x_wb, ids, emb, residual, nsum);

    for (int i = 0; i < N_LAYER; i++) {
        dim3 g1(NTOK / 64, 1024 / 128);
        k_gemm1_mfma<<<g1, 256, 0, stream>>>(residual, nsum, norm_w + i * D_MODEL,
                                             in_wb + (size_t)i * 262144, xh, zb);
        k_cxs<<<NTOK / 16, 256, 0, stream>>>(
            xh, conv_w + (size_t)i * 512 * 4, conv_b + (size_t)i * 512,
            x_wb + (size_t)i * 24576, dt_w + (size_t)i * 512 * 16,
            dt_b + (size_t)i * 512, a_log + (size_t)i * 512 * 16,
            xb, dbc, Aprod, Hfin);
        k_scanB<<<NSC / 64, 64, 0, stream>>>(Aprod, Hfin);
        k_scanC<<<(1024 * NC) / 64, 64, 0, stream>>>(
            xb, zb, dbc, dt_w + (size_t)i * 512 * 16, dt_b + (size_t)i * 512,
            a_log + (size_t)i * 512 * 16, d_skip + (size_t)i * 512, Hfin, yb);
        dim3 g2(NTOK / 64, 256 / 64);
        k_gemm2_mfma<<<g2, 256, 0, stream>>>(yb, out_wb + (size_t)i * 131072,
                                             residual, nsum);
    }

    k_rmshead<<<NTOK, 256, 0, stream>>>(residual, norm_f, lm_w, out);
}

// Round 10
// 1121.634 us; speedup vs baseline: 1.2873x; 1.0845x over previous
//
#include <hip/hip_runtime.h>
#include <hip/hip_bf16.h>

#define D_MODEL 256
#define N_LAYER 16
#define VOCAB 24
#define D_INNER 512
#define D_STATE 16
#define D_CONV 4
#define DT_RANK 16
#define BATCH 2
#define SEQ 2048
#define NTOK (BATCH*SEQ)   /* 4096 */
#define EPS 1e-5f
#define NC 128             /* scan chunks per sequence */
#define CL (SEQ/NC)        /* 16 tokens per chunk */
#define NSC (BATCH*D_INNER*D_STATE)      /* 16384 scan chains */
#define WCVT_BLOCKS 26112  /* 6,684,672 / 256 */

typedef __hip_bfloat16 bf16;
typedef __attribute__((ext_vector_type(8))) short short8;
typedef __attribute__((ext_vector_type(4))) float f32x4;

__device__ __forceinline__ float silu(float v) { return v / (1.f + __expf(-v)); }
__device__ __forceinline__ float bf2f(bf16 v) { return __bfloat162float(v); }
__device__ __forceinline__ float bfs2f(short s) {         // raw bf16 bits -> f32
    return __uint_as_float(((unsigned)(unsigned short)s) << 16);
}
__device__ __forceinline__ short bfr(float x) {           // f32 -> bf16 RNE
    unsigned u = __float_as_uint(x);
    return (short)((u + 0x7fffu + ((u >> 16) & 1u)) >> 16);
}

// dt-rank dot, 4-way tree (MUST be identical in scanA and scanC paths)
__device__ __forceinline__ float dtdot(const float* __restrict__ rv,
                                       const float* __restrict__ wdt, float bias) {
    float p0 = bias, p1 = 0.f, p2 = 0.f, p3 = 0.f;
    #pragma unroll
    for (int r = 0; r < 4; r++) {
        p0 = fmaf(rv[r*4 + 0], wdt[r*4 + 0], p0);
        p1 = fmaf(rv[r*4 + 1], wdt[r*4 + 1], p1);
        p2 = fmaf(rv[r*4 + 2], wdt[r*4 + 2], p2);
        p3 = fmaf(rv[r*4 + 3], wdt[r*4 + 3], p3);
    }
    return (p0 + p1) + (p2 + p3);
}

// ---- init: weight bf16 pre-convert (blocks 0..26111) + embedding w/ nsum seed
__global__ void k_init(const float* __restrict__ in_w, const float* __restrict__ out_w,
                       const float* __restrict__ x_w, short* __restrict__ in_wb,
                       short* __restrict__ out_wb, short* __restrict__ x_wb,
                       const int* __restrict__ ids, const float* __restrict__ emb,
                       float* __restrict__ residual, float* __restrict__ nsum) {
    __shared__ float wred[4];
    if (blockIdx.x < WCVT_BLOCKS) {
        int idx = blockIdx.x * 256 + threadIdx.x;      // 6,684,672 total
        if (idx < 4194304) {
            in_wb[idx] = bfr(in_w[idx]);
        } else if (idx < 4194304 + 2097152) {
            int j = idx - 4194304;
            out_wb[j] = bfr(out_w[j]);
        } else {
            int j = idx - 4194304 - 2097152;           // < 393216
            x_wb[j] = bfr(x_w[j]);
        }
    } else {
        int tok = blockIdx.x - WCVT_BLOCKS, c = threadIdx.x;
        float v = emb[ids[tok] * D_MODEL + c];
        residual[tok * 256 + c] = v;
        float s = v * v;
        #pragma unroll
        for (int off = 32; off >= 1; off >>= 1) s += __shfl_xor(s, off);
        if ((c & 63) == 0) wred[c >> 6] = s;
        __syncthreads();
        if (c == 0) {
            float tot = wred[0] + wred[1] + wred[2] + wred[3];
            *(float4*)(nsum + (size_t)tok * 4) = make_float4(tot, 0.f, 0.f, 0.f);
        }
    }
}

// ---- gemm1 MFMA with FUSED rmsnorm, N-tile 128 (grid.y=8) [R8-verified]
__global__ __launch_bounds__(256) void k_gemm1_mfma(const float* __restrict__ Rres,
                                                    const float* __restrict__ nsum,
                                                    const float* __restrict__ nw,
                                                    const short* __restrict__ W16,
                                                    bf16* __restrict__ xh,
                                                    bf16* __restrict__ zb) {
    __shared__ short AsL[64 * 40];    // A tile [64 rows][32k pad->40]
    __shared__ short WsL[128 * 40];   // W tile [128 rows][32k pad->40]
    const int bm = blockIdx.x * 64, bn = blockIdx.y * 128;
    const int tid = threadIdx.x;
    const int wave = tid >> 6, lane = tid & 63;
    const int wm = (wave & 1) * 32, wn = (wave >> 1) * 32;
    const int quad = lane >> 4, lr = lane & 15;
    const int srow = tid >> 2, skq = (tid & 3) * 8;
    const float4 ns = *(const float4*)(nsum + (size_t)(bm + srow) * 4);
    const float scale = rsqrtf((ns.x + ns.y + ns.z + ns.w) * (1.f / 256.f) + EPS);
    f32x4 acc[2][2][2] = {};          // [nb][mi][ni]
    for (int k0 = 0; k0 < 256; k0 += 32) {
        float av[8], wv[8];
        *(float4*)&av[0] = *(const float4*)(Rres + (size_t)(bm + srow) * 256 + k0 + skq);
        *(float4*)&av[4] = *(const float4*)(Rres + (size_t)(bm + srow) * 256 + k0 + skq + 4);
        *(float4*)&wv[0] = *(const float4*)(nw + k0 + skq);
        *(float4*)&wv[4] = *(const float4*)(nw + k0 + skq + 4);
        short8 a8;
        #pragma unroll
        for (int j = 0; j < 8; j++) a8[j] = bfr(av[j] * scale * wv[j]);
        short8 w8[2];
        w8[0] = *(const short8*)(W16 + (size_t)(bn + srow) * 256 + k0 + skq);
        w8[1] = *(const short8*)(W16 + (size_t)(bn + 64 + srow) * 256 + k0 + skq);
        __syncthreads();
        *(short8*)&AsL[srow * 40 + skq] = a8;
        *(short8*)&WsL[srow * 40 + skq] = w8[0];
        *(short8*)&WsL[(64 + srow) * 40 + skq] = w8[1];
        __syncthreads();
        short8 af[2], bf[2][2];
        #pragma unroll
        for (int i = 0; i < 2; i++)
            af[i] = *(const short8*)&AsL[(wm + i * 16 + lr) * 40 + quad * 8];
        #pragma unroll
        for (int nb = 0; nb < 2; nb++)
            #pragma unroll
            for (int i = 0; i < 2; i++)
                bf[nb][i] = *(const short8*)&WsL[(nb * 64 + wn + i * 16 + lr) * 40 + quad * 8];
        #pragma unroll
        for (int nb = 0; nb < 2; nb++)
            #pragma unroll
            for (int mi = 0; mi < 2; mi++)
                #pragma unroll
                for (int ni = 0; ni < 2; ni++)
                    acc[nb][mi][ni] = __builtin_amdgcn_mfma_f32_16x16x32_bf16(
                        af[mi], bf[nb][ni], acc[nb][mi][ni], 0, 0, 0);
    }
    #pragma unroll
    for (int nb = 0; nb < 2; nb++) {
        #pragma unroll
        for (int mi = 0; mi < 2; mi++) {
            #pragma unroll
            for (int ni = 0; ni < 2; ni++) {
                int gcol = bn + nb * 64 + wn + ni * 16 + lr;
                #pragma unroll
                for (int r = 0; r < 4; r++) {
                    int grow = bm + wm + mi * 16 + quad * 4 + r;
                    float v = acc[nb][mi][ni][r];
                    if (gcol < 512) xh[(size_t)grow * 512 + gcol] = __float2bfloat16(v);
                    else            zb[(size_t)grow * 512 + gcol - 512] = __float2bfloat16(v);
                }
            }
        }
    }
}

// ---- gemm2 MFMA (BK=32) + fused nsum epilogue [R3-verified]
__global__ __launch_bounds__(256) void k_gemm2_mfma(const bf16* __restrict__ Abf,
                                                    const short* __restrict__ W16,
                                                    float* __restrict__ residual,
                                                    float* __restrict__ nsum) {
    __shared__ short AsL[64 * 40];
    __shared__ short WsL[64 * 40];
    __shared__ float rsum[64][2];
    const short* A16 = (const short*)Abf;
    const int bm = blockIdx.x * 64, bn = blockIdx.y * 64;
    const int tid = threadIdx.x;
    const int wave = tid >> 6, lane = tid & 63;
    const int wm = (wave & 1) * 32, wn = (wave >> 1) * 32;
    const int quad = lane >> 4, lr = lane & 15;
    const int srow = tid >> 2, skq = (tid & 3) * 8;
    f32x4 acc[2][2] = {};
    for (int k0 = 0; k0 < 512; k0 += 32) {
        short8 a8 = *(const short8*)(A16 + (size_t)(bm + srow) * 512 + k0 + skq);
        short8 w8 = *(const short8*)(W16 + (size_t)(bn + srow) * 512 + k0 + skq);
        __syncthreads();
        *(short8*)&AsL[srow * 40 + skq] = a8;
        *(short8*)&WsL[srow * 40 + skq] = w8;
        __syncthreads();
        short8 af[2], bf[2];
        #pragma unroll
        for (int i = 0; i < 2; i++) {
            af[i] = *(const short8*)&AsL[(wm + i * 16 + lr) * 40 + quad * 8];
            bf[i] = *(const short8*)&WsL[(wn + i * 16 + lr) * 40 + quad * 8];
        }
        #pragma unroll
        for (int mi = 0; mi < 2; mi++)
            #pragma unroll
            for (int ni = 0; ni < 2; ni++)
                acc[mi][ni] = __builtin_amdgcn_mfma_f32_16x16x32_bf16(
                    af[mi], bf[ni], acc[mi][ni], 0, 0, 0);
    }
    float sq[2][4] = {};
    #pragma unroll
    for (int mi = 0; mi < 2; mi++) {
        #pragma unroll
        for (int ni = 0; ni < 2; ni++) {
            int gcol = bn + wn + ni * 16 + lr;
            #pragma unroll
            for (int r = 0; r < 4; r++) {
                int grow = bm + wm + mi * 16 + quad * 4 + r;
                size_t idx = (size_t)grow * 256 + gcol;
                float v = residual[idx] + acc[mi][ni][r];
                residual[idx] = v;
                sq[mi][r] += v * v;
            }
        }
    }
    #pragma unroll
    for (int off = 1; off < 16; off <<= 1) {
        #pragma unroll
        for (int mi = 0; mi < 2; mi++)
            #pragma unroll
            for (int r = 0; r < 4; r++)
                sq[mi][r] += __shfl_xor(sq[mi][r], off);
    }
    if (lr == 0) {
        #pragma unroll
        for (int mi = 0; mi < 2; mi++)
            #pragma unroll
            for (int r = 0; r < 4; r++)
                rsum[wm + mi * 16 + quad * 4 + r][wave >> 1] = sq[mi][r];
    }
    __syncthreads();
    if (tid < 64)
        nsum[(size_t)(bm + tid) * 4 + blockIdx.y] = rsum[tid][0] + rsum[tid][1];
}

// ---- FUSED conv+silu + x_proj MFMA + scanA [R9-verified structure; dtr tree'd]
__global__ __launch_bounds__(256) void k_cxs(const bf16* __restrict__ xh,
                                             const float* __restrict__ cw,
                                             const float* __restrict__ cb,
                                             const short* __restrict__ W16,
                                             const float* __restrict__ dtw,
                                             const float* __restrict__ dtb,
                                             const float* __restrict__ a_log,
                                             bf16* __restrict__ xb,
                                             float* __restrict__ dbc,
                                             float* __restrict__ Aprod,
                                             float* __restrict__ Hfin) {
    __shared__ short Cs[16][520];            // conv output tile, pad 512->520
    __shared__ float Ds[16][52];             // dbc tile, 48 cols pad->52
    const int bm = blockIdx.x * 16;          // token tile == scan chunk
    const int tid = threadIdx.x;
    const int wave = tid >> 6, lane = tid & 63;
    const int quad = lane >> 4, lr = lane & 15;
    const int wn = wave * 16;

    short8 wreg[16];
    if (wn < 48) {
        const short* wp = W16 + (size_t)(wn + lr) * 512 + quad * 8;
        #pragma unroll
        for (int k = 0; k < 16; k++) wreg[k] = *(const short8*)(wp + k * 32);
    }

    // ---- conv prologue: thread = (8 d-lanes, 4 token rows)
    {
        const int d8 = (tid & 63) * 8;
        const int rg = (tid >> 6) * 4;           // 0,4,8,12
        const int lbase = (bm & 2047) + rg;
        const int gbase = bm + rg;
        float xv[7][8];
        #pragma unroll
        for (int i = 0; i < 7; i++) {
            int l = lbase - 3 + i;
            if (l >= 0) {
                short8 r8 = *(const short8*)((const short*)xh +
                               (size_t)(gbase - 3 + i) * 512 + d8);
                #pragma unroll
                for (int j = 0; j < 8; j++) xv[i][j] = bfs2f(r8[j]);
            } else {
                #pragma unroll
                for (int j = 0; j < 8; j++) xv[i][j] = 0.f;
            }
        }
        float cwv[8][4], cbv[8];
        #pragma unroll
        for (int j = 0; j < 8; j++) {
            *(float4*)&cwv[j][0] = *(const float4*)(cw + (d8 + j) * 4);
            cbv[j] = cb[d8 + j];
        }
        #pragma unroll
        for (int t = 0; t < 4; t++) {
            short8 o;
            #pragma unroll
            for (int j = 0; j < 8; j++) {
                float acc = cbv[j] + xv[t][j] * cwv[j][0] + xv[t+1][j] * cwv[j][1]
                                   + xv[t+2][j] * cwv[j][2] + xv[t+3][j] * cwv[j][3];
                o[j] = bfr(silu(acc));
            }
            *(short8*)&Cs[rg + t][d8] = o;
            *(short8*)((short*)xb + (size_t)(gbase + t) * 512 + d8) = o;
        }
    }
    __syncthreads();

    // ---- xproj MFMA (waves 0..2), results -> dbc global + Ds LDS
    if (wn < 48) {
        f32x4 acc = {};
        #pragma unroll
        for (int k = 0; k < 16; k++) {
            short8 af = *(const short8*)&Cs[lr][k * 32 + quad * 8];
            acc = __builtin_amdgcn_mfma_f32_16x16x32_bf16(af, wreg[k], acc, 0, 0, 0);
        }
        int gcol = wn + lr;
        #pragma unroll
        for (int r = 0; r < 4; r++) {
            float v = acc[r];
            dbc[(size_t)(bm + quad * 4 + r) * 48 + gcol] = v;
            Ds[quad * 4 + r][gcol] = v;
        }
    }
    __syncthreads();

    // ---- scan phase A: 512 chains, 2 per thread (d = tid, tid+256), chunk c
    {
        const int b = bm >> 11;
        const int c = (bm & 2047) >> 4;
        float A[2][16], h[2][16], ap[2][16], wdt[2][16], bdt[2];
        #pragma unroll
        for (int ch = 0; ch < 2; ch++) {
            int d = tid + ch * 256;
            #pragma unroll
            for (int q = 0; q < 4; q++)
                *(float4*)&wdt[ch][q*4] = *(const float4*)(dtw + d * 16 + q * 4);
            #pragma unroll
            for (int s = 0; s < 16; s++) {
                A[ch][s] = -__expf(a_log[d * 16 + s]);
                h[ch][s] = 0.f; ap[ch][s] = 1.f;
            }
            bdt[ch] = dtb[d];
        }
        for (int t = 0; t < CL; t++) {
            float dtc[16], Bc[16];
            #pragma unroll
            for (int r = 0; r < 16; r++) dtc[r] = Ds[t][r];       // broadcast
            #pragma unroll
            for (int s = 0; s < 16; s++) Bc[s] = Ds[t][16 + s];   // broadcast
            #pragma unroll
            for (int ch = 0; ch < 2; ch++) {
                int d = tid + ch * 256;
                float dtr = dtdot(dtc, wdt[ch], bdt[ch]);
                float dtv = (dtr > 20.f) ? dtr : __logf(1.f + __expf(dtr));
                float u = dtv * bfs2f(((const short*)&Cs[t][0])[d]);
                #pragma unroll
                for (int s = 0; s < 16; s++) {
                    float dA = __expf(dtv * A[ch][s]);
                    h[ch][s] = fmaf(dA, h[ch][s], u * Bc[s]);
                    ap[ch][s] *= dA;
                }
            }
        }
        #pragma unroll
        for (int ch = 0; ch < 2; ch++) {
            int d = tid + ch * 256;
            int bd = b * 512 + d;
            float* Ap = Aprod + (size_t)c * NSC + (size_t)bd * 16;
            float* Hp = Hfin  + (size_t)c * NSC + (size_t)bd * 16;
            #pragma unroll
            for (int q = 0; q < 4; q++) {
                *(float4*)(Ap + q * 4) = make_float4(ap[ch][q*4], ap[ch][q*4+1],
                                                     ap[ch][q*4+2], ap[ch][q*4+3]);
                *(float4*)(Hp + q * 4) = make_float4(h[ch][q*4], h[ch][q*4+1],
                                                     h[ch][q*4+2], h[ch][q*4+3]);
            }
        }
    }
}

// ---------------- scan phase B: serial combine over chunks, register-batched
__global__ __launch_bounds__(64) void k_scanB(const float* __restrict__ Aprod,
                                              float* __restrict__ Hfin) {
    int chain = blockIdx.x * 64 + threadIdx.x;     // NSC
    float h = 0.f;
    for (int cg = 0; cg < NC; cg += 16) {
        float a[16], f[16];
        #pragma unroll
        for (int j = 0; j < 16; j++) {
            size_t i = (size_t)(cg + j) * NSC + chain;
            a[j] = Aprod[i];
            f[j] = Hfin[i];
        }
        #pragma unroll
        for (int j = 0; j < 16; j++) {
            size_t i = (size_t)(cg + j) * NSC + chain;
            Hfin[i] = h;
            h = fmaf(a[j], h, f[j]);
        }
    }
}

// -------- scan phase C: rescan from start state. dbc tile staged in LDS once
// per block (1 wave, all lanes same token rows -> broadcast reads); dt
// recomputed with the SAME tree order as scanA.
__global__ __launch_bounds__(64) void k_scanC(const bf16* __restrict__ xb,
                                              const bf16* __restrict__ zb,
                                              const float* __restrict__ dbc,
                                              const float* __restrict__ dtw,
                                              const float* __restrict__ dtb,
                                              const float* __restrict__ a_log,
                                              const float* __restrict__ Dp,
                                              const float* __restrict__ Hstart,
                                              bf16* __restrict__ yb) {
    __shared__ float DbcS[16 * 48];                // 3 KB: this chunk's dbc rows
    int gid = blockIdx.x * 64 + threadIdx.x;       // 131072
    int bd = gid & 1023;
    int c = gid >> 10;
    int d = bd & 511, b = bd >> 9;
    int tok0 = b * SEQ + c * CL;
    // ---- cooperative stage: 192 float4 total, 3 per thread, coalesced
    {
        const float4* src = (const float4*)(dbc + (size_t)tok0 * 48);
        float4* dst = (float4*)DbcS;
        #pragma unroll
        for (int q = 0; q < 3; q++)
            dst[q * 64 + threadIdx.x] = src[q * 64 + threadIdx.x];
    }
    float A[16], h[16], wdt[16];
    const float* Hp = Hstart + (size_t)c * NSC + bd * 16;
    #pragma unroll
    for (int q = 0; q < 4; q++)
        *(float4*)&wdt[q*4] = *(const float4*)(dtw + d * 16 + q * 4);
    #pragma unroll
    for (int s = 0; s < 16; s++) {
        A[s] = -__expf(a_log[d * 16 + s]);
        h[s] = Hp[s];
    }
    float bdt = dtb[d];
    float Dv = Dp[d];
    const bf16* xp = xb + (size_t)tok0 * 512 + d;
    const bf16* zp = zb + (size_t)tok0 * 512 + d;
    bf16* yp = yb + (size_t)tok0 * 512 + d;
    __syncthreads();
    for (int t = 0; t < CL; t++) {
        float rv[48];                              // dt 0..15, B 16..31, C 32..47
        #pragma unroll
        for (int q = 0; q < 12; q++)
            *(float4*)&rv[q*4] = *(const float4*)&DbcS[t * 48 + q * 4];
        float dtr = dtdot(rv, wdt, bdt);
        float dtv = (dtr > 20.f) ? dtr : __logf(1.f + __expf(dtr));
        float xv = bf2f(xp[t * 512]);
        float u = dtv * xv;
        float sum = 0.f;
        #pragma unroll
        for (int s = 0; s < 16; s++) {
            float dA = __expf(dtv * A[s]);
            h[s] = fmaf(dA, h[s], u * rv[16 + s]);
            sum = fmaf(h[s], rv[32 + s], sum);
        }
        float zv = bf2f(zp[t * 512]);
        yp[t * 512] = __float2bfloat16((sum + Dv * xv) * silu(zv));
    }
}

// ---- final rmsnorm + lm head fused: hn never leaves the block
__global__ void k_rmshead(const float* __restrict__ residual, const float* __restrict__ w,
                          const float* __restrict__ lw, float* __restrict__ out) {
    __shared__ float wred[4];
    __shared__ float hrow[256];
    int tok = blockIdx.x, c = threadIdx.x;
    float v = residual[tok * 256 + c];
    float s = v * v;
    #pragma unroll
    for (int off = 32; off >= 1; off >>= 1) s += __shfl_xor(s, off);
    if ((c & 63) == 0) wred[c >> 6] = s;
    __syncthreads();
    float tot = wred[0] + wred[1] + wred[2] + wred[3];
    float scale = rsqrtf(tot * (1.f / 256.f) + EPS);
    hrow[c] = bfs2f(bfr(v * scale * w[c]));    // bf16-rounded, same as old hn path
    __syncthreads();
    int wave = c >> 6, lane = c & 63;
    float4 hl = *(const float4*)&hrow[lane * 4];
    #pragma unroll
    for (int j = 0; j < 5; j++) {
        int vv = wave * 5 + j;
        float4 wl = *(const float4*)(lw + (size_t)vv * 256 + lane * 4);
        float p = hl.x * wl.x + hl.y * wl.y + hl.z * wl.z + hl.w * wl.w;
        #pragma unroll
        for (int off = 32; off >= 1; off >>= 1) p += __shfl_xor(p, off);
        if (lane == 0) out[(size_t)tok * 20 + vv] = p;
    }
}

extern "C" void kernel_launch(void* const* d_in, const int* in_sizes, int n_in,
                              void* d_out, int out_size, void* d_ws, size_t ws_size,
                              hipStream_t stream) {
    const int*   ids    = (const int*)d_in[0];
    const float* emb    = (const float*)d_in[1];
    const float* in_w   = (const float*)d_in[2];
    const float* conv_w = (const float*)d_in[3];
    const float* conv_b = (const float*)d_in[4];
    const float* x_w    = (const float*)d_in[5];
    const float* dt_w   = (const float*)d_in[6];
    const float* dt_b   = (const float*)d_in[7];
    const float* a_log  = (const float*)d_in[8];
    const float* d_skip = (const float*)d_in[9];
    const float* out_w  = (const float*)d_in[10];
    const float* norm_w = (const float*)d_in[11];
    const float* norm_f = (const float*)d_in[12];
    const float* lm_w   = (const float*)d_in[13];
    float* out = (float*)d_out;

    // ---- workspace layout ----
    char* ws = (char*)d_ws;
    float* residual = (float*)(ws + 0);            // 4 MB
    bf16*  xh       = (bf16*) (ws + 6291456);      // 4 MB (alias: yb)
    bf16*  zb       = (bf16*) (ws + 10485760);     // 4 MB
    bf16*  xb       = (bf16*) (ws + 14680064);     // 4 MB
    float* dbc      = (float*)(ws + 18874368);     // 768 KB
    float* Aprod    = (float*)(ws + 23855104);     // 8 MB
    float* Hfin     = (float*)(ws + 32243712);     // 8 MB
    short* in_wb    = (short*)(ws + 40632320);     // 8 MB  (16 layers bf16)
    short* out_wb   = (short*)(ws + 49020928);     // 4 MB
    short* x_wb     = (short*)(ws + 53215232);     // 768 KB
    float* nsum     = (float*)(ws + 54001664);     // 64 KB [tok][4]
    bf16*  yb       = xh;

    k_init<<<WCVT_BLOCKS + NTOK, 256, 0, stream>>>(in_w, out_w, x_w, in_wb, out_wb,
                                                   x_wb, ids, emb, residual, nsum);

    for (int i = 0; i < N_LAYER; i++) {
        dim3 g1(NTOK / 64, 1024 / 128);
        k_gemm1_mfma<<<g1, 256, 0, stream>>>(residual, nsum, norm_w + i * D_MODEL,
                                             in_wb + (size_t)i * 262144, xh, zb);
        k_cxs<<<NTOK / 16, 256, 0, stream>>>(
            xh, conv_w + (size_t)i * 512 * 4, conv_b + (size_t)i * 512,
            x_wb + (size_t)i * 24576, dt_w + (size_t)i * 512 * 16,
            dt_b + (size_t)i * 512, a_log + (size_t)i * 512 * 16,
            xb, dbc, Aprod, Hfin);
        k_scanB<<<NSC / 64, 64, 0, stream>>>(Aprod, Hfin);
        k_scanC<<<(1024 * NC) / 64, 64, 0, stream>>>(
            xb, zb, dbc, dt_w + (size_t)i * 512 * 16, dt_b + (size_t)i * 512,
            a_log + (size_t)i * 512 * 16, d_skip + (size_t)i * 512, Hfin, yb);
        dim3 g2(NTOK / 64, 256 / 64);
        k_gemm2_mfma<<<g2, 256, 0, stream>>>(yb, out_wb + (size_t)i * 131072,
                                             residual, nsum);
    }

    k_rmshead<<<NTOK, 256, 0, stream>>>(residual, norm_f, lm_w, out);
}